// Round 5
// baseline (6733.208 us; speedup 1.0000x reference)
//
#include <hip/hip_runtime.h>
#include <cmath>

#define HH 542
#define KH 271
#define NPIX (HH*HH)          // 293764
#define BB 8
#define CC3 3
#define NCH (BB*CC3)          // 24 real channels
#define NP 12                 // 12 packed complex planes
#define MROWS (NP*HH)         // 6504 complex rows per pass
#define KSZ 31
#define KRAD 15
#define NF 8
#define FS 3

#define NSPLIT 3
#define NGRP 40               // 20 re + 20 im groups of 16 v1 (covers 5 bx * 64)
#define BTSZ (NGRP*NSPLIT*17*512)  // shorts per fragment-ordered B-table

typedef __attribute__((ext_vector_type(8))) short short8v;
typedef __attribute__((ext_vector_type(4))) float float4v;

static __device__ __forceinline__ float2 cmul(float2 a, float2 b) {
    return make_float2(a.x*b.x - a.y*b.y, a.x*b.y + a.y*b.x);
}

static __device__ __forceinline__ void pair_chans(int p, int& n1, int& n2) {
    if (p < 8) { n1 = 3*p;     n2 = 3*p + 1; }
    else       { int q = p-8; n1 = 6*q + 2; n2 = 6*q + 5; }
}

// truncation 3-way bf16 split of two adjacent floats -> packed shorts (lo=x, hi=y)
static __device__ __forceinline__ void split_pack_pair(float x, float y,
        unsigned& p0, unsigned& p1, unsigned& p2) {
    unsigned ux = __float_as_uint(x), uy = __float_as_uint(y);
    float rx1 = x - __uint_as_float(ux & 0xffff0000u);
    float ry1 = y - __uint_as_float(uy & 0xffff0000u);
    unsigned vx1 = __float_as_uint(rx1), vy1 = __float_as_uint(ry1);
    float rx2 = rx1 - __uint_as_float(vx1 & 0xffff0000u);
    float ry2 = ry1 - __uint_as_float(vy1 & 0xffff0000u);
    p0 = __builtin_amdgcn_perm(uy, ux, 0x07060302u);
    p1 = __builtin_amdgcn_perm(vy1, vx1, 0x07060302u);
    p2 = __builtin_amdgcn_perm(__float_as_uint(ry2), __float_as_uint(rx2), 0x07060302u);
}

// ---------------- tables: tw542 + fragment-ordered split-bf16 B tables.
// Bt[((g*3+s)*17+step)*512 + lane*8 + j] = split_s of B'[n = g*16 + (lane&15)]
//                                               [k' = step*32 + (lane>>4)*8 + j]
__global__ void gen_tables(float2* tw542, short* Btf, short* Bti) {
    int idx = blockIdx.x*blockDim.x + threadIdx.x;
    const float PI2 = 6.283185307179586f;
    if (idx < HH) {
        float ang = -PI2*(float)idx/(float)HH;
        float s, c; sincosf(ang, &s, &c);
        tw542[idx] = make_float2(c, s);
    }
    if (idx >= BTSZ) return;
    int j    = idx & 7;
    int lane = (idx >> 3) & 63;
    int rem  = idx >> 9;
    int step = rem % 17;
    int rem2 = rem / 17;
    int s    = rem2 % 3;
    int g    = rem2 / 3;
    if (g >= NGRP) return;
    int o  = (g >= 20) ? 1 : 0;
    int v1 = (g - 20*o)*16 + (lane & 15);
    int kq = step*32 + (lane >> 4)*8 + j;
    int kidx = kq >> 1, c = kq & 1;
    float wre = 0.f, wim = 0.f;
    if (v1 < KH && kidx < KH) {
        int r = (kidx*v1) % KH;
        float ang = -PI2*(float)r/(float)KH;
        float sn, cs; sincosf(ang, &sn, &cs);
        wre = cs; wim = sn;
    }
    float vf = (o==0) ? ((c==0) ? wre : -wim) : ((c==0) ?  wim : wre);
    float vi = (o==0) ? ((c==0) ? wre :  wim) : ((c==0) ? -wim : wre);
    {
        unsigned u = __float_as_uint(vf);
        unsigned h0 = u & 0xffff0000u;
        float r1 = vf - __uint_as_float(h0);
        unsigned h1 = __float_as_uint(r1) & 0xffff0000u;
        float r2 = r1 - __uint_as_float(h1);
        unsigned sp = (s==0) ? h0 : (s==1) ? h1 : (__float_as_uint(r2) & 0xffff0000u);
        Btf[idx] = (short)(sp >> 16);
    }
    {
        unsigned u = __float_as_uint(vi);
        unsigned h0 = u & 0xffff0000u;
        float r1 = vi - __uint_as_float(h0);
        unsigned h1 = __float_as_uint(r1) & 0xffff0000u;
        float r2 = r1 - __uint_as_float(h1);
        unsigned sp = (s==0) ? h0 : (s==1) ? h1 : (__float_as_uint(r2) & 0xffff0000u);
        Bti[idx] = (short)(sp >> 16);
    }
}

// ---------------- edgetaper alpha vectors (closed-form autocorrelation)
__global__ void alpha_kernel(const float* __restrict__ kk, float* __restrict__ valpha) {
    int b = blockIdx.x;
    int t = threadIdx.x;
    __shared__ float proj[2][KSZ];
    __shared__ float ac[2][KSZ];
    const float* kb = kk + b*KSZ*KSZ;
    if (t < KSZ) {
        float s = 0;
        for (int j = 0; j < KSZ; j++) s += kb[t*KSZ + j];
        proj[0][t] = s;
    } else if (t >= 32 && t < 32+KSZ) {
        int j = t - 32;
        float s = 0;
        for (int i = 0; i < KSZ; i++) s += kb[i*KSZ + j];
        proj[1][j] = s;
    }
    __syncthreads();
    if (t < KSZ) {
        float s0 = 0, s1 = 0;
        for (int m = 0; m + t < KSZ; m++) {
            s0 += proj[0][m]*proj[0][m+t];
            s1 += proj[1][m]*proj[1][m+t];
        }
        ac[0][t] = s0; ac[1][t] = s1;
    }
    __syncthreads();
    float inv0 = 1.0f/ac[0][0];
    float inv1 = 1.0f/ac[1][0];
    for (int d = t; d < HH; d += blockDim.x) {
        for (int a = 0; a < 2; a++) {
            float z;
            if (d <= 30)                   z = ac[a][d];
            else if (d >= 511 && d <= 540) z = ac[a][541-d];
            else if (d == 541)             z = ac[a][0];
            else                           z = 0.0f;
            valpha[(b*2 + a)*HH + d] = 1.0f - z*(a ? inv1 : inv0);
        }
    }
}

// ---------------- Dk = psf2otf(k) via two small DFT stages (mod-free indexing)
__global__ void dk_stage1(const float* __restrict__ kk, const float2* __restrict__ tw,
                          float2* __restrict__ T1) {
    int idx = blockIdx.x*blockDim.x + threadIdx.x;
    if (idx >= BB*KSZ*HH) return;
    int v  = idx % HH;
    int bm = idx / HH;
    int m  = bm % KSZ;
    int b  = bm / KSZ;
    const float* kb = kk + (b*KSZ + m)*KSZ;
    float2 acc = make_float2(0.f, 0.f);
    int r = (KRAD*(HH - v)) % HH;          // (-15 v) mod 542
    for (int n = 0; n < KSZ; n++) {
        float2 w = tw[r];
        float kv = kb[n];
        acc.x = fmaf(kv, w.x, acc.x);
        acc.y = fmaf(kv, w.y, acc.y);
        r += v; if (r >= HH) r -= HH;
    }
    T1[idx] = acc;
}

__global__ void dk_stage2(const float2* __restrict__ T1, const float2* __restrict__ tw,
                          float2* __restrict__ Dk) {
    int idx = blockIdx.x*blockDim.x + threadIdx.x;
    if (idx >= BB*NPIX) return;
    int uv = idx % NPIX;
    int b  = idx / NPIX;
    int u  = uv / HH;
    int v  = uv - u*HH;
    float2 acc = make_float2(0.f, 0.f);
    int r = (KRAD*(HH - u)) % HH;          // (-15 u) mod 542
    const float2* t1 = T1 + (size_t)b*KSZ*HH + v;
    for (int m = 0; m < KSZ; m++) {
        float2 w = tw[r];
        float2 t = t1[(size_t)m*HH];
        acc.x += t.x*w.x - t.y*w.y;
        acc.y += t.x*w.y + t.y*w.x;
        r += u; if (r >= HH) r -= HH;
    }
    Dk[idx] = acc;
}

// ---------------- Dg_sum[c][u][v] = exp(lam)*sum_f |DFT(filt[f,c])|^2 (mod-free)
__global__ void dgs_kernel(const float* __restrict__ filt, const float* __restrict__ lamp,
                           const float2* __restrict__ tw, float* __restrict__ Dgs) {
    int uv = blockIdx.x*blockDim.x + threadIdx.x;
    if (uv >= NPIX) return;
    int u = uv / HH;
    int v = uv - u*HH;
    float el = expf(lamp[0]);
    float2 wu[3], wv[3];
    wu[0] = tw[u ? HH-u : 0]; wu[1] = make_float2(1.f,0.f); wu[2] = tw[u];
    wv[0] = tw[v ? HH-v : 0]; wv[1] = make_float2(1.f,0.f); wv[2] = tw[v];
    float2 ph[3][3];
    #pragma unroll
    for (int m = 0; m < 3; m++)
        #pragma unroll
        for (int n = 0; n < 3; n++)
            ph[m][n] = cmul(wu[m], wv[n]);
    for (int c = 0; c < CC3; c++) {
        float s = 0.f;
        for (int f = 0; f < NF; f++) {
            float2 acc = make_float2(0.f, 0.f);
            const float* fp = filt + ((f*CC3 + c)*FS)*FS;
            #pragma unroll
            for (int m = 0; m < 3; m++)
                #pragma unroll
                for (int n = 0; n < 3; n++) {
                    float fv = fp[m*3+n];
                    acc.x = fmaf(fv, ph[m][n].x, acc.x);
                    acc.y = fmaf(fv, ph[m][n].y, acc.y);
                }
            s = fmaf(acc.x, acc.x, fmaf(acc.y, acc.y, s));
        }
        Dgs[c*NPIX + uv] = s*el;
    }
}

// ---------------- edge-replicate pad + pack pairs
__global__ void pad_pack(const float* __restrict__ y, float* __restrict__ R0,
                         float2* __restrict__ CA) {
    int idx = blockIdx.x*blockDim.x + threadIdx.x;
    if (idx >= NP*NPIX) return;
    int uv = idx % NPIX;
    int p  = idx / NPIX;
    int n1, n2; pair_chans(p, n1, n2);
    int i = uv / HH, j = uv - i*HH;
    int yi = min(max(i - KRAD, 0), 511);
    int yj = min(max(j - KRAD, 0), 511);
    int yo = yi*512 + yj;
    float v1 = y[(size_t)n1*262144 + yo];
    float v2 = y[(size_t)n2*262144 + yo];
    R0[(size_t)n1*NPIX + uv] = v1;
    R0[(size_t)n2*NPIX + uv] = v2;
    CA[idx] = make_float2(v1, v2);
}

// ---------------- Hermitian unpack, per-channel multiply, repack.
__global__ void specmul(const float2* __restrict__ CA, const float2* __restrict__ Dk,
                        const float* __restrict__ Dgs, float2* __restrict__ CB, int mode) {
    int idx = blockIdx.x*blockDim.x + threadIdx.x;
    if (idx >= NP*NPIX) return;
    int uv = idx % NPIX;
    int p  = idx / NPIX;
    int n1, n2; pair_chans(p, n1, n2);
    int b1 = n1/3, c1 = n1 - 3*b1;
    int b2 = n2/3, c2 = n2 - 3*b2;
    int i = uv / HH, j = uv - i*HH;
    int ni = i ? HH - i : 0;
    int nj = j ? HH - j : 0;
    float2 Z  = CA[(size_t)p*NPIX + uv];
    float2 Zm = CA[(size_t)p*NPIX + ni*HH + nj];
    float2 F1 = make_float2(0.5f*(Z.x + Zm.x), 0.5f*(Z.y - Zm.y));
    float2 F2 = make_float2(0.5f*(Z.y + Zm.y), 0.5f*(Zm.x - Z.x));
    float2 d1 = Dk[(size_t)b1*NPIX + uv];
    float2 d2 = Dk[(size_t)b2*NPIX + uv];
    float2 M1, M2;
    if (mode == 0) {
        M1 = d1; M2 = d2;
    } else {
        float o1 = 1.0f/(d1.x*d1.x + d1.y*d1.y + Dgs[(size_t)c1*NPIX + uv]);
        float o2 = 1.0f/(d2.x*d2.x + d2.y*d2.y + Dgs[(size_t)c2*NPIX + uv]);
        M1 = make_float2(d1.x*o1, -d1.y*o1);
        M2 = make_float2(d2.x*o2, -d2.y*o2);
    }
    float2 W1 = cmul(M1, F1);
    float2 W2 = cmul(M2, F2);
    CB[idx] = make_float2(W1.x - W2.y, W1.y + W2.x);
}

// ---------------- MFMA DFT pass, barrier-free K-loop.
// A loaded direct from global in fragment order (stride-2 even/odd decimation),
// 3-way bf16 split in registers; B from fragment-ordered table. Block tile:
// 64 real rows (32 complex) x 64 v1. Epilogue: twiddle combine + chunked LDS
// transpose + coalesced writes, with optional fused blend / final-output.
// mode: 0 = plain transposed write, 1 = edgetaper blend (R0,valp), 2 = out
__global__ void __launch_bounds__(256)
fft_mfma(const float2* __restrict__ Ain, float2* __restrict__ Aout,
         const short* __restrict__ Bt, const float2* __restrict__ tw542,
         const float* __restrict__ valp, float* __restrict__ R0,
         float* __restrict__ outbuf, float scale, int conjtw, int mode)
{
    __shared__ float2 Ts[16][34];

    int id = blockIdx.x;
    int xcd = id & 7, jj = id >> 3;
    int lin = xcd*128 + jj;            // same-by blocks adjacent per XCD
    if (lin >= 1020) return;
    int by = lin / 5, bx = lin - 5*by;

    int tid = threadIdx.x;
    int wid = tid >> 6, lane = tid & 63;
    int wxm = wid & 1, wy = wid >> 1;
    int l15 = lane & 15, quad = lane >> 4;

    // A fragment row pointers (parity folded in)
    const float2* pA[2]; int lim[2];
    #pragma unroll
    for (int mt = 0; mt < 2; mt++) {
        int Rl = wxm*32 + mt*16 + l15;
        int cr = by*32 + (Rl >> 1);
        int par = Rl & 1;
        int crc = (cr < MROWS) ? cr : 0;
        pA[mt] = Ain + (size_t)crc*HH + par;
        lim[mt] = HH - par;
    }
    // B fragment pointers: ct = g*2+im over 2 v1-groups (wy half)
    const short* pB[4];
    #pragma unroll
    for (int ct = 0; ct < 4; ct++) {
        int g = bx*4 + wy*2 + (ct >> 1) + ((ct & 1) ? 20 : 0);
        pB[ct] = Bt + (size_t)g*(3*17*512) + lane*8;
    }

    float4v acc[2][4];
    #pragma unroll
    for (int mt = 0; mt < 2; mt++)
        #pragma unroll
        for (int ct = 0; ct < 4; ct++)
            acc[mt][ct] = (float4v)(0.f);

    float2 Ar[2][2][4];
    short8v Bf[2][4][3];

    auto loadA = [&](int buf, int step) {
        int os = step*32 + 8*quad;
        #pragma unroll
        for (int mt = 0; mt < 2; mt++)
            #pragma unroll
            for (int t = 0; t < 4; t++) {
                int e = os + 2*t;
                e = (e < lim[mt]) ? e : 0;   // pad region: B is 0 there
                Ar[buf][mt][t] = pA[mt][e];
            }
    };
    auto loadB = [&](int buf, int step) {
        #pragma unroll
        for (int ct = 0; ct < 4; ct++)
            #pragma unroll
            for (int s = 0; s < 3; s++)
                Bf[buf][ct][s] = *(const short8v*)(pB[ct] + ((s*17 + step) << 9));
    };

    loadA(0, 0); loadB(0, 0);

    for (int step = 0; step < 17; step++) {
        int cur = step & 1, nxt = cur ^ 1;
        if (step < 16) { loadA(nxt, step+1); loadB(nxt, step+1); }

        union U8 { unsigned u[4]; short8v v; };
        U8 af[2][3];
        #pragma unroll
        for (int mt = 0; mt < 2; mt++)
            #pragma unroll
            for (int t = 0; t < 4; t++)
                split_pack_pair(Ar[cur][mt][t].x, Ar[cur][mt][t].y,
                                af[mt][0].u[t], af[mt][1].u[t], af[mt][2].u[t]);

        #pragma unroll
        for (int sa = 0; sa < 3; sa++)
            #pragma unroll
            for (int sb = 0; sb + sa < 3; sb++)
                #pragma unroll
                for (int mt = 0; mt < 2; mt++)
                    #pragma unroll
                    for (int ct = 0; ct < 4; ct++)
                        acc[mt][ct] = __builtin_amdgcn_mfma_f32_16x16x32_bf16(
                            af[mt][sa].v, Bf[cur][ct][sb], acc[mt][ct], 0, 0, 0);
    }

    // ---- epilogue: per-chunk twiddle combine + LDS transpose + coalesced write
    float2 tg[2];
    #pragma unroll
    for (int g = 0; g < 2; g++) {
        int v1g = bx*64 + wy*32 + g*16 + l15;
        tg[g] = tw542[(v1g < HH) ? v1g : 0];
        if (conjtw) tg[g].y = -tg[g].y;
    }

    for (int half = 0; half < 2; half++) {
        for (int c = 0; c < 4; c++) {
            if (bx*64 + c*16 >= KH) continue;      // uniform skip
            if (wy == (c >> 1)) {
                int g = c & 1;
                #pragma unroll
                for (int mt = 0; mt < 2; mt++)
                    #pragma unroll
                    for (int pr = 0; pr < 2; pr++) {
                        float Ere = acc[mt][g*2  ][2*pr], Ore = acc[mt][g*2  ][2*pr+1];
                        float Eim = acc[mt][g*2+1][2*pr], Oim = acc[mt][g*2+1][2*pr+1];
                        float tOre = tg[g].x*Ore - tg[g].y*Oim;
                        float tOim = tg[g].x*Oim + tg[g].y*Ore;
                        float2 v = half
                            ? make_float2((Ere - tOre)*scale, (Eim - tOim)*scale)
                            : make_float2((Ere + tOre)*scale, (Eim + tOim)*scale);
                        Ts[l15][wxm*16 + mt*8 + quad*2 + pr] = v;
                    }
            }
            __syncthreads();
            int rowv = tid >> 4;
            int c0 = (tid & 15)*2;
            int v1o = bx*64 + c*16 + rowv;
            if (v1o < KH) {
                int vout = v1o + half*KH;
                #pragma unroll
                for (int j2 = 0; j2 < 2; j2++) {
                    int colloc = c0 + j2;
                    int r = by*32 + colloc;
                    if (r < MROWS) {
                        int plane = r / HH;
                        int scol = r - plane*HH;
                        float2 val = Ts[rowv][colloc];
                        size_t sp = (size_t)vout*HH + scol;
                        if (mode == 0) {
                            Aout[(size_t)plane*NPIX + sp] = val;
                        } else if (mode == 1) {
                            int n1, n2; pair_chans(plane, n1, n2);
                            int b1 = n1/3, b2 = n2/3;
                            float a1 = valp[b1*2*HH + vout]*valp[(b1*2+1)*HH + scol];
                            float a2 = valp[b2*2*HH + vout]*valp[(b2*2+1)*HH + scol];
                            size_t s1 = (size_t)n1*NPIX + sp;
                            size_t s2 = (size_t)n2*NPIX + sp;
                            float o1 = R0[s1], o2 = R0[s2];
                            float nv1 = fmaf(a1, o1 - val.x, val.x);
                            float nv2 = fmaf(a2, o2 - val.y, val.y);
                            R0[s1] = nv1; R0[s2] = nv2;
                            Aout[(size_t)plane*NPIX + sp] = make_float2(nv1, nv2);
                        } else {
                            int n1, n2; pair_chans(plane, n1, n2);
                            outbuf[(size_t)n1*NPIX + sp] = val.x;
                            outbuf[(size_t)n2*NPIX + sp] = val.y;
                        }
                    }
                }
            }
            __syncthreads();
        }
    }
}

extern "C" void kernel_launch(void* const* d_in, const int* in_sizes, int n_in,
                              void* d_out, int out_size, void* d_ws, size_t ws_size,
                              hipStream_t stream) {
    const float* y    = (const float*)d_in[0];
    const float* k    = (const float*)d_in[1];
    const float* lam  = (const float*)d_in[2];
    const float* filt = (const float*)d_in[3];
    float* out = (float*)d_out;

    char* base = (char*)d_ws;
    size_t off = 0;
    auto alloc = [&](size_t bytes) {
        void* p = base + off;
        off = (off + bytes + 511) & ~(size_t)511;
        return p;
    };
    float2* CA   = (float2*)alloc(sizeof(float2)*(size_t)NP*NPIX);
    float2* CB   = (float2*)alloc(sizeof(float2)*(size_t)NP*NPIX);
    float*  R0   = (float*) alloc(sizeof(float)*(size_t)NCH*NPIX);
    float2* Dk   = (float2*)alloc(sizeof(float2)*(size_t)BB*NPIX);
    float2* T1   = (float2*)alloc(sizeof(float2)*(size_t)BB*KSZ*HH);
    float*  Dgs  = (float*) alloc(sizeof(float)*(size_t)CC3*NPIX);
    short*  Btf  = (short*) alloc(sizeof(short)*(size_t)BTSZ);
    short*  Bti  = (short*) alloc(sizeof(short)*(size_t)BTSZ);
    float2* tw   = (float2*)alloc(sizeof(float2)*(size_t)HH);
    float*  valp = (float*) alloc(sizeof(float)*(size_t)BB*2*HH);
    (void)ws_size; (void)in_sizes; (void)n_in; (void)out_size;

    const int TPB = 256;
    auto nb = [](long n) { return (int)((n + 255)/256); };

    gen_tables<<<nb((long)BTSZ), TPB, 0, stream>>>(tw, Btf, Bti);
    alpha_kernel<<<BB, 64, 0, stream>>>(k, valp);
    dk_stage1<<<nb((long)BB*KSZ*HH), TPB, 0, stream>>>(k, tw, T1);
    dk_stage2<<<nb((long)BB*NPIX), TPB, 0, stream>>>(T1, tw, Dk);
    dgs_kernel<<<nb((long)NPIX), TPB, 0, stream>>>(filt, lam, tw, Dgs);
    pad_pack<<<nb((long)NP*NPIX), TPB, 0, stream>>>(y, R0, CA);

    const int FG = 1024;   // 8 XCDs x 128 (1020 active)
    const float isc = 1.0f/(float)HH;
    float2 *S = CA, *T = CB;
    // forward fft2: spectrum in S
    fft_mfma<<<FG, TPB, 0, stream>>>(S, T, Btf, tw, valp, R0, out, 1.0f, 0, 0);
    fft_mfma<<<FG, TPB, 0, stream>>>(T, S, Btf, tw, valp, R0, out, 1.0f, 0, 0);
    for (int it = 0; it < 3; it++) {
        specmul<<<nb((long)NP*NPIX), TPB, 0, stream>>>(S, Dk, Dgs, T, 0);
        fft_mfma<<<FG, TPB, 0, stream>>>(T, S, Bti, tw, valp, R0, out, isc, 1, 0);
        fft_mfma<<<FG, TPB, 0, stream>>>(S, T, Bti, tw, valp, R0, out, isc, 1, 1);  // fused blend -> T,R0
        fft_mfma<<<FG, TPB, 0, stream>>>(T, S, Btf, tw, valp, R0, out, 1.0f, 0, 0);
        fft_mfma<<<FG, TPB, 0, stream>>>(S, T, Btf, tw, valp, R0, out, 1.0f, 0, 0); // spectrum -> T
        float2* tmp = S; S = T; T = tmp;
    }
    specmul<<<nb((long)NP*NPIX), TPB, 0, stream>>>(S, Dk, Dgs, T, 1);
    fft_mfma<<<FG, TPB, 0, stream>>>(T, S, Bti, tw, valp, R0, out, isc, 1, 0);
    fft_mfma<<<FG, TPB, 0, stream>>>(S, T, Bti, tw, valp, R0, out, isc, 1, 2);      // fused final out
}

// Round 6
// 1356.079 us; speedup vs baseline: 4.9652x; 4.9652x over previous
//
#include <hip/hip_runtime.h>
#include <cmath>

#define HH 542
#define KH 271
#define NPIX (HH*HH)          // 293764
#define BB 8
#define CC3 3
#define NCH (BB*CC3)          // 24 real channels
#define NP 12                 // 12 packed complex planes
#define MROWS (NP*HH)         // 6504 complex rows per pass
#define MR2 (2*MROWS)         // 13008 real GEMM rows
#define KSZ 31
#define KRAD 15
#define NF 8
#define FS 3

#define NSPLIT 3
#define NGRP 36               // 576 phys cols / 16
#define BTSZ (NGRP*NSPLIT*17*512)  // shorts per fragment-ordered B-table

typedef __attribute__((ext_vector_type(8))) short short8v;
typedef __attribute__((ext_vector_type(4))) float float4v;

static __device__ __forceinline__ float2 cmul(float2 a, float2 b) {
    return make_float2(a.x*b.x - a.y*b.y, a.x*b.y + a.y*b.x);
}

static __device__ __forceinline__ void pair_chans(int p, int& n1, int& n2) {
    if (p < 8) { n1 = 3*p;     n2 = 3*p + 1; }
    else       { int q = p-8; n1 = 6*q + 2; n2 = 6*q + 5; }
}

// truncation 3-way bf16 split of two adjacent values (x=low short, y=high short)
static __device__ __forceinline__ void split_pack_pair(float x, float y,
        unsigned& p0, unsigned& p1, unsigned& p2) {
    unsigned ux = __float_as_uint(x), uy = __float_as_uint(y);
    unsigned hx0 = ux & 0xffff0000u, hy0 = uy & 0xffff0000u;
    float rx1 = x - __uint_as_float(hx0);
    float ry1 = y - __uint_as_float(hy0);
    unsigned hx1 = __float_as_uint(rx1) & 0xffff0000u;
    unsigned hy1 = __float_as_uint(ry1) & 0xffff0000u;
    float rx2 = rx1 - __uint_as_float(hx1);
    float ry2 = ry1 - __uint_as_float(hy1);
    p0 = (hx0 >> 16) | hy0;
    p1 = (hx1 >> 16) | hy1;
    p2 = (__float_as_uint(rx2) >> 16) | (__float_as_uint(ry2) & 0xffff0000u);
}

// ---------------- tables: tw542 + fragment-ordered split-bf16 B tables.
// Bt[((g*3+s)*17+step)*512 + lane*8 + j] = split_s of B'[n = g*16 + (lane&15)]
//                                               [k' = step*32 + (lane>>4)*8 + j]
__global__ void gen_tables(float2* tw542, short* Btf, short* Bti) {
    int idx = blockIdx.x*blockDim.x + threadIdx.x;
    const float PI2 = 6.283185307179586f;
    if (idx < HH) {
        float ang = -PI2*(float)idx/(float)HH;
        float s, c; sincosf(ang, &s, &c);
        tw542[idx] = make_float2(c, s);
    }
    if (idx >= BTSZ) return;
    int j    = idx & 7;
    int lane = (idx >> 3) & 63;
    int rem  = idx >> 9;
    int step = rem % 17;
    int rem2 = rem / 17;
    int s    = rem2 % 3;
    int g    = rem2 / 3;
    if (g >= NGRP) return;
    int n  = g*16 + (lane & 15);
    int kq = step*32 + (lane >> 4)*8 + j;
    int o  = (n >= 288) ? 1 : 0;
    int v1 = n - 288*o;
    int kidx = kq >> 1, c = kq & 1;
    float wre = 0.f, wim = 0.f;
    if (v1 < KH && kidx < KH) {
        int r = (kidx*v1) % KH;
        float ang = -PI2*(float)r/(float)KH;
        float sn, cs; sincosf(ang, &sn, &cs);
        wre = cs; wim = sn;
    }
    float vf = (o==0) ? ((c==0) ? wre : -wim) : ((c==0) ?  wim : wre);
    float vi = (o==0) ? ((c==0) ? wre :  wim) : ((c==0) ? -wim : wre);
    {
        unsigned u = __float_as_uint(vf);
        unsigned h0 = u & 0xffff0000u;
        float r1 = vf - __uint_as_float(h0);
        unsigned h1 = __float_as_uint(r1) & 0xffff0000u;
        float r2 = r1 - __uint_as_float(h1);
        unsigned sp = (s==0) ? h0 : (s==1) ? h1 : (__float_as_uint(r2) & 0xffff0000u);
        Btf[idx] = (short)(sp >> 16);
    }
    {
        unsigned u = __float_as_uint(vi);
        unsigned h0 = u & 0xffff0000u;
        float r1 = vi - __uint_as_float(h0);
        unsigned h1 = __float_as_uint(r1) & 0xffff0000u;
        float r2 = r1 - __uint_as_float(h1);
        unsigned sp = (s==0) ? h0 : (s==1) ? h1 : (__float_as_uint(r2) & 0xffff0000u);
        Bti[idx] = (short)(sp >> 16);
    }
}

// ---------------- edgetaper alpha vectors (closed-form autocorrelation)
__global__ void alpha_kernel(const float* __restrict__ kk, float* __restrict__ valpha) {
    int b = blockIdx.x;
    int t = threadIdx.x;
    __shared__ float proj[2][KSZ];
    __shared__ float ac[2][KSZ];
    const float* kb = kk + b*KSZ*KSZ;
    if (t < KSZ) {
        float s = 0;
        for (int j = 0; j < KSZ; j++) s += kb[t*KSZ + j];
        proj[0][t] = s;
    } else if (t >= 32 && t < 32+KSZ) {
        int j = t - 32;
        float s = 0;
        for (int i = 0; i < KSZ; i++) s += kb[i*KSZ + j];
        proj[1][j] = s;
    }
    __syncthreads();
    if (t < KSZ) {
        float s0 = 0, s1 = 0;
        for (int m = 0; m + t < KSZ; m++) {
            s0 += proj[0][m]*proj[0][m+t];
            s1 += proj[1][m]*proj[1][m+t];
        }
        ac[0][t] = s0; ac[1][t] = s1;
    }
    __syncthreads();
    float inv0 = 1.0f/ac[0][0];
    float inv1 = 1.0f/ac[1][0];
    for (int d = t; d < HH; d += blockDim.x) {
        for (int a = 0; a < 2; a++) {
            float z;
            if (d <= 30)                   z = ac[a][d];
            else if (d >= 511 && d <= 540) z = ac[a][541-d];
            else if (d == 541)             z = ac[a][0];
            else                           z = 0.0f;
            valpha[(b*2 + a)*HH + d] = 1.0f - z*(a ? inv1 : inv0);
        }
    }
}

// ---------------- Dk = psf2otf(k) via two small DFT stages (mod-free indexing)
__global__ void dk_stage1(const float* __restrict__ kk, const float2* __restrict__ tw,
                          float2* __restrict__ T1) {
    int idx = blockIdx.x*blockDim.x + threadIdx.x;
    if (idx >= BB*KSZ*HH) return;
    int v  = idx % HH;
    int bm = idx / HH;
    int m  = bm % KSZ;
    int b  = bm / KSZ;
    const float* kb = kk + (b*KSZ + m)*KSZ;
    float2 acc = make_float2(0.f, 0.f);
    int r = (KRAD*(HH - v)) % HH;          // (-15 v) mod 542
    for (int n = 0; n < KSZ; n++) {
        float2 w = tw[r];
        float kv = kb[n];
        acc.x = fmaf(kv, w.x, acc.x);
        acc.y = fmaf(kv, w.y, acc.y);
        r += v; if (r >= HH) r -= HH;
    }
    T1[idx] = acc;
}

__global__ void dk_stage2(const float2* __restrict__ T1, const float2* __restrict__ tw,
                          float2* __restrict__ Dk) {
    int idx = blockIdx.x*blockDim.x + threadIdx.x;
    if (idx >= BB*NPIX) return;
    int uv = idx % NPIX;
    int b  = idx / NPIX;
    int u  = uv / HH;
    int v  = uv - u*HH;
    float2 acc = make_float2(0.f, 0.f);
    int r = (KRAD*(HH - u)) % HH;          // (-15 u) mod 542
    const float2* t1 = T1 + (size_t)b*KSZ*HH + v;
    for (int m = 0; m < KSZ; m++) {
        float2 w = tw[r];
        float2 t = t1[(size_t)m*HH];
        acc.x += t.x*w.x - t.y*w.y;
        acc.y += t.x*w.y + t.y*w.x;
        r += u; if (r >= HH) r -= HH;
    }
    Dk[idx] = acc;
}

// ---------------- Dg_sum[c][u][v] = exp(lam)*sum_f |DFT(filt[f,c])|^2 (mod-free)
__global__ void dgs_kernel(const float* __restrict__ filt, const float* __restrict__ lamp,
                           const float2* __restrict__ tw, float* __restrict__ Dgs) {
    int uv = blockIdx.x*blockDim.x + threadIdx.x;
    if (uv >= NPIX) return;
    int u = uv / HH;
    int v = uv - u*HH;
    float el = expf(lamp[0]);
    float2 wu[3], wv[3];
    wu[0] = tw[u ? HH-u : 0]; wu[1] = make_float2(1.f,0.f); wu[2] = tw[u];
    wv[0] = tw[v ? HH-v : 0]; wv[1] = make_float2(1.f,0.f); wv[2] = tw[v];
    float2 ph[3][3];
    #pragma unroll
    for (int m = 0; m < 3; m++)
        #pragma unroll
        for (int n = 0; n < 3; n++)
            ph[m][n] = cmul(wu[m], wv[n]);
    for (int c = 0; c < CC3; c++) {
        float s = 0.f;
        for (int f = 0; f < NF; f++) {
            float2 acc = make_float2(0.f, 0.f);
            const float* fp = filt + ((f*CC3 + c)*FS)*FS;
            #pragma unroll
            for (int m = 0; m < 3; m++)
                #pragma unroll
                for (int n = 0; n < 3; n++) {
                    float fv = fp[m*3+n];
                    acc.x = fmaf(fv, ph[m][n].x, acc.x);
                    acc.y = fmaf(fv, ph[m][n].y, acc.y);
                }
            s = fmaf(acc.x, acc.x, fmaf(acc.y, acc.y, s));
        }
        Dgs[c*NPIX + uv] = s*el;
    }
}

// ---------------- edge-replicate pad + pack pairs
__global__ void pad_pack(const float* __restrict__ y, float* __restrict__ R0,
                         float2* __restrict__ CA) {
    int idx = blockIdx.x*blockDim.x + threadIdx.x;
    if (idx >= NP*NPIX) return;
    int uv = idx % NPIX;
    int p  = idx / NPIX;
    int n1, n2; pair_chans(p, n1, n2);
    int i = uv / HH, j = uv - i*HH;
    int yi = min(max(i - KRAD, 0), 511);
    int yj = min(max(j - KRAD, 0), 511);
    int yo = yi*512 + yj;
    float v1 = y[(size_t)n1*262144 + yo];
    float v2 = y[(size_t)n2*262144 + yo];
    R0[(size_t)n1*NPIX + uv] = v1;
    R0[(size_t)n2*NPIX + uv] = v2;
    CA[idx] = make_float2(v1, v2);
}

// ---------------- Hermitian unpack, per-channel multiply, repack.
__global__ void specmul(const float2* __restrict__ CA, const float2* __restrict__ Dk,
                        const float* __restrict__ Dgs, float2* __restrict__ CB, int mode) {
    int idx = blockIdx.x*blockDim.x + threadIdx.x;
    if (idx >= NP*NPIX) return;
    int uv = idx % NPIX;
    int p  = idx / NPIX;
    int n1, n2; pair_chans(p, n1, n2);
    int b1 = n1/3, c1 = n1 - 3*b1;
    int b2 = n2/3, c2 = n2 - 3*b2;
    int i = uv / HH, j = uv - i*HH;
    int ni = i ? HH - i : 0;
    int nj = j ? HH - j : 0;
    float2 Z  = CA[(size_t)p*NPIX + uv];
    float2 Zm = CA[(size_t)p*NPIX + ni*HH + nj];
    float2 F1 = make_float2(0.5f*(Z.x + Zm.x), 0.5f*(Z.y - Zm.y));
    float2 F2 = make_float2(0.5f*(Z.y + Zm.y), 0.5f*(Zm.x - Z.x));
    float2 d1 = Dk[(size_t)b1*NPIX + uv];
    float2 d2 = Dk[(size_t)b2*NPIX + uv];
    float2 M1, M2;
    if (mode == 0) {
        M1 = d1; M2 = d2;
    } else {
        float o1 = 1.0f/(d1.x*d1.x + d1.y*d1.y + Dgs[(size_t)c1*NPIX + uv]);
        float o2 = 1.0f/(d2.x*d2.x + d2.y*d2.y + Dgs[(size_t)c2*NPIX + uv]);
        M1 = make_float2(d1.x*o1, -d1.y*o1);
        M2 = make_float2(d2.x*o2, -d2.y*o2);
    }
    float2 W1 = cmul(M1, F1);
    float2 W2 = cmul(M2, F2);
    CB[idx] = make_float2(W1.x - W2.y, W1.y + W2.x);
}

// ---------------- MFMA DFT pass (R4 structure). A staged+split in LDS; B
// fragments from L2-resident fragment-ordered table; epilogue transposes the
// 32v1 x 64col tile through LDS for coalesced writes, with optional fused
// blend (mode 1) or final output (mode 2). XCD-swizzled grid.
__global__ void __launch_bounds__(256, 3)
fft_mfma(const float2* __restrict__ Ain, float2* __restrict__ Aout,
         const short* __restrict__ Bt, const float2* __restrict__ tw542,
         const float* __restrict__ valp, float* __restrict__ R0,
         float* __restrict__ outbuf, float scale, int conjtw, int mode)
{
    __shared__ short As[NSPLIT*128*40];   // 30720 B; reused as float2 Ts[32][65] in epilogue
    const int APL = 128*40;

    // XCD-locality swizzle: all 9 bx of a by-group on one XCD, adjacent in time
    int id = blockIdx.x;
    int xcd = id & 7, jj = id >> 3;
    int lin = xcd*115 + jj;
    if (lin >= 918) return;
    int by = lin / 9, bx = lin - 9*by;

    int tid = threadIdx.x;
    int arow = tid >> 3, ai4 = tid & 7;     // A staging roles
    int wid = tid >> 6, lane = tid & 63;
    int wxm = wid & 1, wy = wid >> 1;
    int l15 = lane & 15, quad = lane >> 4;

    int aoff0 = (wxm*64 + l15)*40 + quad*8;

    int g_re = bx*2 + wy;                   // 16-col group indices in B-table
    int g_im = 18 + bx*2 + wy;
    const short* BtL = Bt + lane*8;

    float4v acc[4][2];
    #pragma unroll
    for (int mt = 0; mt < 4; mt++)
        #pragma unroll
        for (int ct = 0; ct < 2; ct++)
            acc[mt][ct] = (float4v)(0.f);

    float4 regA[2][2];
    short8v bf_cur[2][3], bf_next[2][3];
    const float4 z4 = make_float4(0.f,0.f,0.f,0.f);

    auto loadA = [&](int step) {
        #pragma unroll
        for (int qq = 0; qq < 2; qq++) {
            int rowg = by*64 + arow + 32*qq;
            bool rvld = rowg < MROWS;
            const float4* rp = (const float4*)Ain + (size_t)(rvld ? rowg : 0)*271;
            int i0 = step*16 + 2*ai4;
            regA[qq][0] = (rvld && i0     < 271) ? rp[i0]   : z4;
            regA[qq][1] = (rvld && i0 + 1 < 271) ? rp[i0+1] : z4;
        }
    };
    auto loadB = [&](int step, short8v dst[2][3]) {
        #pragma unroll
        for (int s = 0; s < 3; s++) {
            dst[0][s] = *(const short8v*)(BtL + (((g_re*3 + s)*17 + step) << 9));
            dst[1][s] = *(const short8v*)(BtL + (((g_im*3 + s)*17 + step) << 9));
        }
    };

    loadA(0); loadB(0, bf_cur);

    for (int step = 0; step < 17; step++) {
        // stage A into LDS with 3-way bf16 split
        #pragma unroll
        for (int qq = 0; qq < 2; qq++) {
            int rl = 2*(arow + 32*qq);
            int offE = rl*40 + 4*ai4;
            float4 f0 = regA[qq][0], f1 = regA[qq][1];
            unsigned e0a,e1a,e2a, e0b,e1b,e2b;
            split_pack_pair(f0.x, f0.y, e0a, e1a, e2a);
            split_pack_pair(f1.x, f1.y, e0b, e1b, e2b);
            *(uint2*)(As + 0*APL + offE) = make_uint2(e0a, e0b);
            *(uint2*)(As + 1*APL + offE) = make_uint2(e1a, e1b);
            *(uint2*)(As + 2*APL + offE) = make_uint2(e2a, e2b);
            unsigned o0a,o1a,o2a, o0b,o1b,o2b;
            split_pack_pair(f0.z, f0.w, o0a, o1a, o2a);
            split_pack_pair(f1.z, f1.w, o0b, o1b, o2b);
            int offO = offE + 40;
            *(uint2*)(As + 0*APL + offO) = make_uint2(o0a, o0b);
            *(uint2*)(As + 1*APL + offO) = make_uint2(o1a, o1b);
            *(uint2*)(As + 2*APL + offO) = make_uint2(o2a, o2b);
        }
        __syncthreads();

        if (step + 1 < 17) { loadA(step+1); loadB(step+1, bf_next); }

        #pragma unroll
        for (int sa = 0; sa < 3; sa++) {
            short8v af[4];
            #pragma unroll
            for (int mt = 0; mt < 4; mt++)
                af[mt] = *(const short8v*)(As + sa*APL + aoff0 + mt*16*40);
            #pragma unroll
            for (int sb = 0; sb + sa < 3; sb++)
                #pragma unroll
                for (int mt = 0; mt < 4; mt++)
                    #pragma unroll
                    for (int ct = 0; ct < 2; ct++)
                        acc[mt][ct] = __builtin_amdgcn_mfma_f32_16x16x32_bf16(
                            af[mt], bf_cur[ct][sb], acc[mt][ct], 0, 0, 0);
        }
        __syncthreads();

        #pragma unroll
        for (int ct = 0; ct < 2; ct++)
            #pragma unroll
            for (int s = 0; s < 3; s++)
                bf_cur[ct][s] = bf_next[ct][s];
    }

    // ---- epilogue: twiddle combine, LDS transpose, coalesced writes (+fusion)
    int v1w = bx*32 + wy*16 + l15;
    float2 t = (v1w < KH) ? tw542[v1w] : make_float2(1.f, 0.f);
    if (conjtw) t.y = -t.y;
    float2* Ts = (float2*)As;    // [32][65] pitch-65 float2 = 16640 B

    #pragma unroll
    for (int half = 0; half < 2; half++) {
        __syncthreads();
        #pragma unroll
        for (int mt = 0; mt < 4; mt++) {
            #pragma unroll
            for (int pr = 0; pr < 2; pr++) {
                float Ere = acc[mt][0][2*pr],   Ore = acc[mt][0][2*pr+1];
                float Eim = acc[mt][1][2*pr],   Oim = acc[mt][1][2*pr+1];
                float tOre = t.x*Ore - t.y*Oim;
                float tOim = t.x*Oim + t.y*Ore;
                int cloc = wxm*32 + mt*8 + quad*2 + pr;
                float2 v = (half == 0)
                    ? make_float2((Ere + tOre)*scale, (Eim + tOim)*scale)
                    : make_float2((Ere - tOre)*scale, (Eim - tOim)*scale);
                Ts[(wy*16 + l15)*65 + cloc] = v;
            }
        }
        __syncthreads();
        int tv = tid >> 3, ti = tid & 7;
        bool v1ok = (bx*32 + tv) < KH;
        int v1 = bx*32 + tv + (half ? KH : 0);
        #pragma unroll
        for (int j = 0; j < 8; j++) {
            int cloc = ti*8 + j;
            int r = by*64 + cloc;
            if (v1ok && r < MROWS) {
                int plane = r / HH;
                int col = r - plane*HH;
                float2 val = Ts[tv*65 + cloc];
                size_t sp = (size_t)v1*HH + col;
                if (mode == 0) {
                    Aout[(size_t)plane*NPIX + sp] = val;
                } else if (mode == 1) {
                    int n1, n2; pair_chans(plane, n1, n2);
                    int b1 = n1/3, b2 = n2/3;
                    float a1 = valp[b1*2*HH + v1]*valp[(b1*2+1)*HH + col];
                    float a2 = valp[b2*2*HH + v1]*valp[(b2*2+1)*HH + col];
                    size_t s1 = (size_t)n1*NPIX + sp;
                    size_t s2 = (size_t)n2*NPIX + sp;
                    float o1 = R0[s1], o2 = R0[s2];
                    float nv1 = fmaf(a1, o1 - val.x, val.x);
                    float nv2 = fmaf(a2, o2 - val.y, val.y);
                    R0[s1] = nv1; R0[s2] = nv2;
                    Aout[(size_t)plane*NPIX + sp] = make_float2(nv1, nv2);
                } else {
                    int n1, n2; pair_chans(plane, n1, n2);
                    outbuf[(size_t)n1*NPIX + sp] = val.x;
                    outbuf[(size_t)n2*NPIX + sp] = val.y;
                }
            }
        }
    }
}

extern "C" void kernel_launch(void* const* d_in, const int* in_sizes, int n_in,
                              void* d_out, int out_size, void* d_ws, size_t ws_size,
                              hipStream_t stream) {
    const float* y    = (const float*)d_in[0];
    const float* k    = (const float*)d_in[1];
    const float* lam  = (const float*)d_in[2];
    const float* filt = (const float*)d_in[3];
    float* out = (float*)d_out;

    char* base = (char*)d_ws;
    size_t off = 0;
    auto alloc = [&](size_t bytes) {
        void* p = base + off;
        off = (off + bytes + 511) & ~(size_t)511;
        return p;
    };
    float2* CA   = (float2*)alloc(sizeof(float2)*(size_t)NP*NPIX);
    float2* CB   = (float2*)alloc(sizeof(float2)*(size_t)NP*NPIX);
    float*  R0   = (float*) alloc(sizeof(float)*(size_t)NCH*NPIX);
    float2* Dk   = (float2*)alloc(sizeof(float2)*(size_t)BB*NPIX);
    float2* T1   = (float2*)alloc(sizeof(float2)*(size_t)BB*KSZ*HH);
    float*  Dgs  = (float*) alloc(sizeof(float)*(size_t)CC3*NPIX);
    short*  Btf  = (short*) alloc(sizeof(short)*(size_t)BTSZ);
    short*  Bti  = (short*) alloc(sizeof(short)*(size_t)BTSZ);
    float2* tw   = (float2*)alloc(sizeof(float2)*(size_t)HH);
    float*  valp = (float*) alloc(sizeof(float)*(size_t)BB*2*HH);
    (void)ws_size; (void)in_sizes; (void)n_in; (void)out_size;

    const int TPB = 256;
    auto nb = [](long n) { return (int)((n + 255)/256); };

    gen_tables<<<nb((long)BTSZ), TPB, 0, stream>>>(tw, Btf, Bti);
    alpha_kernel<<<BB, 64, 0, stream>>>(k, valp);
    dk_stage1<<<nb((long)BB*KSZ*HH), TPB, 0, stream>>>(k, tw, T1);
    dk_stage2<<<nb((long)BB*NPIX), TPB, 0, stream>>>(T1, tw, Dk);
    dgs_kernel<<<nb((long)NPIX), TPB, 0, stream>>>(filt, lam, tw, Dgs);
    pad_pack<<<nb((long)NP*NPIX), TPB, 0, stream>>>(y, R0, CA);

    const int FG = 920;   // 8 XCD groups x 115
    const float isc = 1.0f/(float)HH;
    float2 *S = CA, *T = CB;
    // forward fft2: spectrum in S
    fft_mfma<<<FG, TPB, 0, stream>>>(S, T, Btf, tw, valp, R0, out, 1.0f, 0, 0);
    fft_mfma<<<FG, TPB, 0, stream>>>(T, S, Btf, tw, valp, R0, out, 1.0f, 0, 0);
    for (int it = 0; it < 3; it++) {
        specmul<<<nb((long)NP*NPIX), TPB, 0, stream>>>(S, Dk, Dgs, T, 0);
        fft_mfma<<<FG, TPB, 0, stream>>>(T, S, Bti, tw, valp, R0, out, isc, 1, 0);
        fft_mfma<<<FG, TPB, 0, stream>>>(S, T, Bti, tw, valp, R0, out, isc, 1, 1);  // fused blend -> T,R0
        fft_mfma<<<FG, TPB, 0, stream>>>(T, S, Btf, tw, valp, R0, out, 1.0f, 0, 0);
        fft_mfma<<<FG, TPB, 0, stream>>>(S, T, Btf, tw, valp, R0, out, 1.0f, 0, 0); // spectrum -> T
        float2* tmp = S; S = T; T = tmp;
    }
    specmul<<<nb((long)NP*NPIX), TPB, 0, stream>>>(S, Dk, Dgs, T, 1);
    fft_mfma<<<FG, TPB, 0, stream>>>(T, S, Bti, tw, valp, R0, out, isc, 1, 0);
    fft_mfma<<<FG, TPB, 0, stream>>>(S, T, Bti, tw, valp, R0, out, isc, 1, 2);      // fused final out
}

// Round 7
// 1141.222 us; speedup vs baseline: 5.9000x; 1.1883x over previous
//
#include <hip/hip_runtime.h>
#include <cmath>

#define HH 542
#define KH 271
#define NPIX (HH*HH)          // 293764
#define BB 8
#define CC3 3
#define NCH (BB*CC3)          // 24 real channels
#define NP 12                 // 12 packed complex planes
#define MROWS (NP*HH)         // 6504 complex rows per pass
#define MR2 (2*MROWS)         // 13008 real GEMM rows
#define KSZ 31
#define KRAD 15
#define NF 8
#define FS 3

#define NSPLIT 3
#define NGRP 36               // 576 phys cols / 16
#define BTSZ (NGRP*NSPLIT*17*512)  // shorts per fragment-ordered B-table

typedef __attribute__((ext_vector_type(8))) short short8v;
typedef __attribute__((ext_vector_type(4))) float float4v;

static __device__ __forceinline__ float2 cmul(float2 a, float2 b) {
    return make_float2(a.x*b.x - a.y*b.y, a.x*b.y + a.y*b.x);
}

static __device__ __forceinline__ void pair_chans(int p, int& n1, int& n2) {
    if (p < 8) { n1 = 3*p;     n2 = 3*p + 1; }
    else       { int q = p-8; n1 = 6*q + 2; n2 = 6*q + 5; }
}

// truncation 3-way bf16 split of two adjacent values (x=low short, y=high short)
static __device__ __forceinline__ void split_pack_pair(float x, float y,
        unsigned& p0, unsigned& p1, unsigned& p2) {
    unsigned ux = __float_as_uint(x), uy = __float_as_uint(y);
    unsigned hx0 = ux & 0xffff0000u, hy0 = uy & 0xffff0000u;
    float rx1 = x - __uint_as_float(hx0);
    float ry1 = y - __uint_as_float(hy0);
    unsigned hx1 = __float_as_uint(rx1) & 0xffff0000u;
    unsigned hy1 = __float_as_uint(ry1) & 0xffff0000u;
    float rx2 = rx1 - __uint_as_float(hx1);
    float ry2 = ry1 - __uint_as_float(hy1);
    p0 = (hx0 >> 16) | hy0;
    p1 = (hx1 >> 16) | hy1;
    p2 = (__float_as_uint(rx2) >> 16) | (__float_as_uint(ry2) & 0xffff0000u);
}

// ---------------- tables: tw542 + fragment-ordered split-bf16 B tables.
__global__ void gen_tables(float2* tw542, short* Btf, short* Bti) {
    int idx = blockIdx.x*blockDim.x + threadIdx.x;
    const float PI2 = 6.283185307179586f;
    if (idx < HH) {
        float ang = -PI2*(float)idx/(float)HH;
        float s, c; sincosf(ang, &s, &c);
        tw542[idx] = make_float2(c, s);
    }
    if (idx >= BTSZ) return;
    int j    = idx & 7;
    int lane = (idx >> 3) & 63;
    int rem  = idx >> 9;
    int step = rem % 17;
    int rem2 = rem / 17;
    int s    = rem2 % 3;
    int g    = rem2 / 3;
    if (g >= NGRP) return;
    int n  = g*16 + (lane & 15);
    int kq = step*32 + (lane >> 4)*8 + j;
    int o  = (n >= 288) ? 1 : 0;
    int v1 = n - 288*o;
    int kidx = kq >> 1, c = kq & 1;
    float wre = 0.f, wim = 0.f;
    if (v1 < KH && kidx < KH) {
        int r = (kidx*v1) % KH;
        float ang = -PI2*(float)r/(float)KH;
        float sn, cs; sincosf(ang, &sn, &cs);
        wre = cs; wim = sn;
    }
    float vf = (o==0) ? ((c==0) ? wre : -wim) : ((c==0) ?  wim : wre);
    float vi = (o==0) ? ((c==0) ? wre :  wim) : ((c==0) ? -wim : wre);
    {
        unsigned u = __float_as_uint(vf);
        unsigned h0 = u & 0xffff0000u;
        float r1 = vf - __uint_as_float(h0);
        unsigned h1 = __float_as_uint(r1) & 0xffff0000u;
        float r2 = r1 - __uint_as_float(h1);
        unsigned sp = (s==0) ? h0 : (s==1) ? h1 : (__float_as_uint(r2) & 0xffff0000u);
        Btf[idx] = (short)(sp >> 16);
    }
    {
        unsigned u = __float_as_uint(vi);
        unsigned h0 = u & 0xffff0000u;
        float r1 = vi - __uint_as_float(h0);
        unsigned h1 = __float_as_uint(r1) & 0xffff0000u;
        float r2 = r1 - __uint_as_float(h1);
        unsigned sp = (s==0) ? h0 : (s==1) ? h1 : (__float_as_uint(r2) & 0xffff0000u);
        Bti[idx] = (short)(sp >> 16);
    }
}

// ---------------- edgetaper alpha vectors (closed-form autocorrelation)
__global__ void alpha_kernel(const float* __restrict__ kk, float* __restrict__ valpha) {
    int b = blockIdx.x;
    int t = threadIdx.x;
    __shared__ float proj[2][KSZ];
    __shared__ float ac[2][KSZ];
    const float* kb = kk + b*KSZ*KSZ;
    if (t < KSZ) {
        float s = 0;
        for (int j = 0; j < KSZ; j++) s += kb[t*KSZ + j];
        proj[0][t] = s;
    } else if (t >= 32 && t < 32+KSZ) {
        int j = t - 32;
        float s = 0;
        for (int i = 0; i < KSZ; i++) s += kb[i*KSZ + j];
        proj[1][j] = s;
    }
    __syncthreads();
    if (t < KSZ) {
        float s0 = 0, s1 = 0;
        for (int m = 0; m + t < KSZ; m++) {
            s0 += proj[0][m]*proj[0][m+t];
            s1 += proj[1][m]*proj[1][m+t];
        }
        ac[0][t] = s0; ac[1][t] = s1;
    }
    __syncthreads();
    float inv0 = 1.0f/ac[0][0];
    float inv1 = 1.0f/ac[1][0];
    for (int d = t; d < HH; d += blockDim.x) {
        for (int a = 0; a < 2; a++) {
            float z;
            if (d <= 30)                   z = ac[a][d];
            else if (d >= 511 && d <= 540) z = ac[a][541-d];
            else if (d == 541)             z = ac[a][0];
            else                           z = 0.0f;
            valpha[(b*2 + a)*HH + d] = 1.0f - z*(a ? inv1 : inv0);
        }
    }
}

// ---------------- Dk = psf2otf(k) via two small DFT stages (mod-free indexing)
__global__ void dk_stage1(const float* __restrict__ kk, const float2* __restrict__ tw,
                          float2* __restrict__ T1) {
    int idx = blockIdx.x*blockDim.x + threadIdx.x;
    if (idx >= BB*KSZ*HH) return;
    int v  = idx % HH;
    int bm = idx / HH;
    int m  = bm % KSZ;
    int b  = bm / KSZ;
    const float* kb = kk + (b*KSZ + m)*KSZ;
    float2 acc = make_float2(0.f, 0.f);
    int r = (KRAD*(HH - v)) % HH;
    for (int n = 0; n < KSZ; n++) {
        float2 w = tw[r];
        float kv = kb[n];
        acc.x = fmaf(kv, w.x, acc.x);
        acc.y = fmaf(kv, w.y, acc.y);
        r += v; if (r >= HH) r -= HH;
    }
    T1[idx] = acc;
}

__global__ void dk_stage2(const float2* __restrict__ T1, const float2* __restrict__ tw,
                          float2* __restrict__ Dk) {
    int idx = blockIdx.x*blockDim.x + threadIdx.x;
    if (idx >= BB*NPIX) return;
    int uv = idx % NPIX;
    int b  = idx / NPIX;
    int u  = uv / HH;
    int v  = uv - u*HH;
    float2 acc = make_float2(0.f, 0.f);
    int r = (KRAD*(HH - u)) % HH;
    const float2* t1 = T1 + (size_t)b*KSZ*HH + v;
    for (int m = 0; m < KSZ; m++) {
        float2 w = tw[r];
        float2 t = t1[(size_t)m*HH];
        acc.x += t.x*w.x - t.y*w.y;
        acc.y += t.x*w.y + t.y*w.x;
        r += u; if (r >= HH) r -= HH;
    }
    Dk[idx] = acc;
}

// ---------------- Dg_sum[c][u][v] = exp(lam)*sum_f |DFT(filt[f,c])|^2 (mod-free)
__global__ void dgs_kernel(const float* __restrict__ filt, const float* __restrict__ lamp,
                           const float2* __restrict__ tw, float* __restrict__ Dgs) {
    int uv = blockIdx.x*blockDim.x + threadIdx.x;
    if (uv >= NPIX) return;
    int u = uv / HH;
    int v = uv - u*HH;
    float el = expf(lamp[0]);
    float2 wu[3], wv[3];
    wu[0] = tw[u ? HH-u : 0]; wu[1] = make_float2(1.f,0.f); wu[2] = tw[u];
    wv[0] = tw[v ? HH-v : 0]; wv[1] = make_float2(1.f,0.f); wv[2] = tw[v];
    float2 ph[3][3];
    #pragma unroll
    for (int m = 0; m < 3; m++)
        #pragma unroll
        for (int n = 0; n < 3; n++)
            ph[m][n] = cmul(wu[m], wv[n]);
    for (int c = 0; c < CC3; c++) {
        float s = 0.f;
        for (int f = 0; f < NF; f++) {
            float2 acc = make_float2(0.f, 0.f);
            const float* fp = filt + ((f*CC3 + c)*FS)*FS;
            #pragma unroll
            for (int m = 0; m < 3; m++)
                #pragma unroll
                for (int n = 0; n < 3; n++) {
                    float fv = fp[m*3+n];
                    acc.x = fmaf(fv, ph[m][n].x, acc.x);
                    acc.y = fmaf(fv, ph[m][n].y, acc.y);
                }
            s = fmaf(acc.x, acc.x, fmaf(acc.y, acc.y, s));
        }
        Dgs[c*NPIX + uv] = s*el;
    }
}

// ---------------- edge-replicate pad + pack pairs
__global__ void pad_pack(const float* __restrict__ y, float* __restrict__ R0,
                         float2* __restrict__ CA) {
    int idx = blockIdx.x*blockDim.x + threadIdx.x;
    if (idx >= NP*NPIX) return;
    int uv = idx % NPIX;
    int p  = idx / NPIX;
    int n1, n2; pair_chans(p, n1, n2);
    int i = uv / HH, j = uv - i*HH;
    int yi = min(max(i - KRAD, 0), 511);
    int yj = min(max(j - KRAD, 0), 511);
    int yo = yi*512 + yj;
    float v1 = y[(size_t)n1*262144 + yo];
    float v2 = y[(size_t)n2*262144 + yo];
    R0[(size_t)n1*NPIX + uv] = v1;
    R0[(size_t)n2*NPIX + uv] = v2;
    CA[idx] = make_float2(v1, v2);
}

// ---------------- Hermitian unpack, per-channel multiply, repack.
__global__ void specmul(const float2* __restrict__ CA, const float2* __restrict__ Dk,
                        const float* __restrict__ Dgs, float2* __restrict__ CB, int mode) {
    int idx = blockIdx.x*blockDim.x + threadIdx.x;
    if (idx >= NP*NPIX) return;
    int uv = idx % NPIX;
    int p  = idx / NPIX;
    int n1, n2; pair_chans(p, n1, n2);
    int b1 = n1/3, c1 = n1 - 3*b1;
    int b2 = n2/3, c2 = n2 - 3*b2;
    int i = uv / HH, j = uv - i*HH;
    int ni = i ? HH - i : 0;
    int nj = j ? HH - j : 0;
    float2 Z  = CA[(size_t)p*NPIX + uv];
    float2 Zm = CA[(size_t)p*NPIX + ni*HH + nj];
    float2 F1 = make_float2(0.5f*(Z.x + Zm.x), 0.5f*(Z.y - Zm.y));
    float2 F2 = make_float2(0.5f*(Z.y + Zm.y), 0.5f*(Zm.x - Z.x));
    float2 d1 = Dk[(size_t)b1*NPIX + uv];
    float2 d2 = Dk[(size_t)b2*NPIX + uv];
    float2 M1, M2;
    if (mode == 0) {
        M1 = d1; M2 = d2;
    } else {
        float o1 = 1.0f/(d1.x*d1.x + d1.y*d1.y + Dgs[(size_t)c1*NPIX + uv]);
        float o2 = 1.0f/(d2.x*d2.x + d2.y*d2.y + Dgs[(size_t)c2*NPIX + uv]);
        M1 = make_float2(d1.x*o1, -d1.y*o1);
        M2 = make_float2(d2.x*o2, -d2.y*o2);
    }
    float2 W1 = cmul(M1, F1);
    float2 W2 = cmul(M2, F2);
    CB[idx] = make_float2(W1.x - W2.y, W1.y + W2.x);
}

// ---------------- MFMA DFT pass. A staged+split in LDS; B fragments from
// L2-resident fragment-ordered table; epilogue transposes through LDS and
// writes with WAVE-CONTIGUOUS full-line stores (float4/float2 lane-adjacent).
// mode: 0 = plain transposed write, 1 = fused edgetaper blend, 2 = final out
__global__ void __launch_bounds__(256, 3)
fft_mfma(const float2* __restrict__ Ain, float2* __restrict__ Aout,
         const short* __restrict__ Bt, const float2* __restrict__ tw542,
         const float* __restrict__ valp, float* __restrict__ R0,
         float* __restrict__ outbuf, float scale, int conjtw, int mode)
{
    __shared__ short As[NSPLIT*128*40];   // 30720 B; reused as float2 Ts[32][65] in epilogue
    const int APL = 128*40;

    // XCD-locality swizzle
    int id = blockIdx.x;
    int xcd = id & 7, jj = id >> 3;
    int lin = xcd*115 + jj;
    if (lin >= 918) return;
    int by = lin / 9, bx = lin - 9*by;

    int tid = threadIdx.x;
    int arow = tid >> 3, ai4 = tid & 7;
    int wid = tid >> 6, lane = tid & 63;
    int wxm = wid & 1, wy = wid >> 1;
    int l15 = lane & 15, quad = lane >> 4;

    int aoff0 = (wxm*64 + l15)*40 + quad*8;

    int g_re = bx*2 + wy;
    int g_im = 18 + bx*2 + wy;
    const short* BtL = Bt + lane*8;

    float4v acc[4][2];
    #pragma unroll
    for (int mt = 0; mt < 4; mt++)
        #pragma unroll
        for (int ct = 0; ct < 2; ct++)
            acc[mt][ct] = (float4v)(0.f);

    float4 regA[2][2];
    short8v bf_cur[2][3], bf_next[2][3];
    const float4 z4 = make_float4(0.f,0.f,0.f,0.f);

    auto loadA = [&](int step) {
        #pragma unroll
        for (int qq = 0; qq < 2; qq++) {
            int rowg = by*64 + arow + 32*qq;
            bool rvld = rowg < MROWS;
            const float4* rp = (const float4*)Ain + (size_t)(rvld ? rowg : 0)*271;
            int i0 = step*16 + 2*ai4;
            regA[qq][0] = (rvld && i0     < 271) ? rp[i0]   : z4;
            regA[qq][1] = (rvld && i0 + 1 < 271) ? rp[i0+1] : z4;
        }
    };
    auto loadB = [&](int step, short8v dst[2][3]) {
        #pragma unroll
        for (int s = 0; s < 3; s++) {
            dst[0][s] = *(const short8v*)(BtL + (((g_re*3 + s)*17 + step) << 9));
            dst[1][s] = *(const short8v*)(BtL + (((g_im*3 + s)*17 + step) << 9));
        }
    };

    loadA(0); loadB(0, bf_cur);

    for (int step = 0; step < 17; step++) {
        #pragma unroll
        for (int qq = 0; qq < 2; qq++) {
            int rl = 2*(arow + 32*qq);
            int offE = rl*40 + 4*ai4;
            float4 f0 = regA[qq][0], f1 = regA[qq][1];
            unsigned e0a,e1a,e2a, e0b,e1b,e2b;
            split_pack_pair(f0.x, f0.y, e0a, e1a, e2a);
            split_pack_pair(f1.x, f1.y, e0b, e1b, e2b);
            *(uint2*)(As + 0*APL + offE) = make_uint2(e0a, e0b);
            *(uint2*)(As + 1*APL + offE) = make_uint2(e1a, e1b);
            *(uint2*)(As + 2*APL + offE) = make_uint2(e2a, e2b);
            unsigned o0a,o1a,o2a, o0b,o1b,o2b;
            split_pack_pair(f0.z, f0.w, o0a, o1a, o2a);
            split_pack_pair(f1.z, f1.w, o0b, o1b, o2b);
            int offO = offE + 40;
            *(uint2*)(As + 0*APL + offO) = make_uint2(o0a, o0b);
            *(uint2*)(As + 1*APL + offO) = make_uint2(o1a, o1b);
            *(uint2*)(As + 2*APL + offO) = make_uint2(o2a, o2b);
        }
        __syncthreads();

        if (step + 1 < 17) { loadA(step+1); loadB(step+1, bf_next); }

        #pragma unroll
        for (int sa = 0; sa < 3; sa++) {
            short8v af[4];
            #pragma unroll
            for (int mt = 0; mt < 4; mt++)
                af[mt] = *(const short8v*)(As + sa*APL + aoff0 + mt*16*40);
            #pragma unroll
            for (int sb = 0; sb + sa < 3; sb++)
                #pragma unroll
                for (int mt = 0; mt < 4; mt++)
                    #pragma unroll
                    for (int ct = 0; ct < 2; ct++)
                        acc[mt][ct] = __builtin_amdgcn_mfma_f32_16x16x32_bf16(
                            af[mt], bf_cur[ct][sb], acc[mt][ct], 0, 0, 0);
        }
        __syncthreads();

        #pragma unroll
        for (int ct = 0; ct < 2; ct++)
            #pragma unroll
            for (int s = 0; s < 3; s++)
                bf_cur[ct][s] = bf_next[ct][s];
    }

    // ---- epilogue: twiddle combine, LDS transpose, wave-contiguous writes
    int v1w = bx*32 + wy*16 + l15;
    float2 t = (v1w < KH) ? tw542[v1w] : make_float2(1.f, 0.f);
    if (conjtw) t.y = -t.y;
    float2* Ts = (float2*)As;    // [32][65] pitch-65 float2

    // per-thread output column pair (invariant): lane covers cols c0, c0+1
    int lanec = tid & 31;
    int rowsel = (tid >> 5) & 1;
    int c0 = lanec*2;
    int r0g = by*64 + c0;                 // even; never straddles a plane with +1
    bool rok = r0g < MROWS;
    int plane = rok ? (r0g / HH) : 0;
    int colg = r0g - plane*HH;
    int n1, n2; pair_chans(plane, n1, n2);
    int b1 = n1/3, b2 = n2/3;

    #pragma unroll
    for (int half = 0; half < 2; half++) {
        __syncthreads();
        #pragma unroll
        for (int mt = 0; mt < 4; mt++) {
            #pragma unroll
            for (int pr = 0; pr < 2; pr++) {
                float Ere = acc[mt][0][2*pr],   Ore = acc[mt][0][2*pr+1];
                float Eim = acc[mt][1][2*pr],   Oim = acc[mt][1][2*pr+1];
                float tOre = t.x*Ore - t.y*Oim;
                float tOim = t.x*Oim + t.y*Ore;
                int cloc = wxm*32 + mt*8 + quad*2 + pr;
                float2 v = (half == 0)
                    ? make_float2((Ere + tOre)*scale, (Eim + tOim)*scale)
                    : make_float2((Ere - tOre)*scale, (Eim - tOim)*scale);
                Ts[(wy*16 + l15)*65 + cloc] = v;
            }
        }
        __syncthreads();
        #pragma unroll
        for (int rr = 0; rr < 4; rr++) {
            int row = wid*8 + rr*2 + rowsel;       // 0..31
            int v1r = bx*32 + row;
            if (v1r >= KH || !rok) continue;
            int v1 = v1r + (half ? KH : 0);
            float2 a0 = Ts[row*65 + c0];
            float2 a1 = Ts[row*65 + c0 + 1];
            size_t sp = (size_t)v1*HH + colg;
            if (mode == 0) {
                *(float4*)(Aout + (size_t)plane*NPIX + sp) =
                    make_float4(a0.x, a0.y, a1.x, a1.y);
            } else if (mode == 1) {
                float ar1 = valp[b1*2*HH + v1];
                float ar2 = valp[b2*2*HH + v1];
                float ac1a = valp[(b1*2+1)*HH + colg];
                float ac1b = valp[(b1*2+1)*HH + colg + 1];
                float ac2a = valp[(b2*2+1)*HH + colg];
                float ac2b = valp[(b2*2+1)*HH + colg + 1];
                float2* p1 = (float2*)(R0 + (size_t)n1*NPIX + sp);
                float2* p2 = (float2*)(R0 + (size_t)n2*NPIX + sp);
                float2 o1 = *p1, o2 = *p2;
                float nv1a = fmaf(ar1*ac1a, o1.x - a0.x, a0.x);
                float nv1b = fmaf(ar1*ac1b, o1.y - a1.x, a1.x);
                float nv2a = fmaf(ar2*ac2a, o2.x - a0.y, a0.y);
                float nv2b = fmaf(ar2*ac2b, o2.y - a1.y, a1.y);
                *p1 = make_float2(nv1a, nv1b);
                *p2 = make_float2(nv2a, nv2b);
                *(float4*)(Aout + (size_t)plane*NPIX + sp) =
                    make_float4(nv1a, nv2a, nv1b, nv2b);
            } else {
                *(float2*)(outbuf + (size_t)n1*NPIX + sp) = make_float2(a0.x, a1.x);
                *(float2*)(outbuf + (size_t)n2*NPIX + sp) = make_float2(a0.y, a1.y);
            }
        }
    }
}

extern "C" void kernel_launch(void* const* d_in, const int* in_sizes, int n_in,
                              void* d_out, int out_size, void* d_ws, size_t ws_size,
                              hipStream_t stream) {
    const float* y    = (const float*)d_in[0];
    const float* k    = (const float*)d_in[1];
    const float* lam  = (const float*)d_in[2];
    const float* filt = (const float*)d_in[3];
    float* out = (float*)d_out;

    char* base = (char*)d_ws;
    size_t off = 0;
    auto alloc = [&](size_t bytes) {
        void* p = base + off;
        off = (off + bytes + 511) & ~(size_t)511;
        return p;
    };
    float2* CA   = (float2*)alloc(sizeof(float2)*(size_t)NP*NPIX);
    float2* CB   = (float2*)alloc(sizeof(float2)*(size_t)NP*NPIX);
    float*  R0   = (float*) alloc(sizeof(float)*(size_t)NCH*NPIX);
    float2* Dk   = (float2*)alloc(sizeof(float2)*(size_t)BB*NPIX);
    float2* T1   = (float2*)alloc(sizeof(float2)*(size_t)BB*KSZ*HH);
    float*  Dgs  = (float*) alloc(sizeof(float)*(size_t)CC3*NPIX);
    short*  Btf  = (short*) alloc(sizeof(short)*(size_t)BTSZ);
    short*  Bti  = (short*) alloc(sizeof(short)*(size_t)BTSZ);
    float2* tw   = (float2*)alloc(sizeof(float2)*(size_t)HH);
    float*  valp = (float*) alloc(sizeof(float)*(size_t)BB*2*HH);
    (void)ws_size; (void)in_sizes; (void)n_in; (void)out_size;

    const int TPB = 256;
    auto nb = [](long n) { return (int)((n + 255)/256); };

    gen_tables<<<nb((long)BTSZ), TPB, 0, stream>>>(tw, Btf, Bti);
    alpha_kernel<<<BB, 64, 0, stream>>>(k, valp);
    dk_stage1<<<nb((long)BB*KSZ*HH), TPB, 0, stream>>>(k, tw, T1);
    dk_stage2<<<nb((long)BB*NPIX), TPB, 0, stream>>>(T1, tw, Dk);
    dgs_kernel<<<nb((long)NPIX), TPB, 0, stream>>>(filt, lam, tw, Dgs);
    pad_pack<<<nb((long)NP*NPIX), TPB, 0, stream>>>(y, R0, CA);

    const int FG = 920;   // 8 XCD groups x 115
    const float isc = 1.0f/(float)HH;
    float2 *S = CA, *T = CB;
    fft_mfma<<<FG, TPB, 0, stream>>>(S, T, Btf, tw, valp, R0, out, 1.0f, 0, 0);
    fft_mfma<<<FG, TPB, 0, stream>>>(T, S, Btf, tw, valp, R0, out, 1.0f, 0, 0);
    for (int it = 0; it < 3; it++) {
        specmul<<<nb((long)NP*NPIX), TPB, 0, stream>>>(S, Dk, Dgs, T, 0);
        fft_mfma<<<FG, TPB, 0, stream>>>(T, S, Bti, tw, valp, R0, out, isc, 1, 0);
        fft_mfma<<<FG, TPB, 0, stream>>>(S, T, Bti, tw, valp, R0, out, isc, 1, 1);
        fft_mfma<<<FG, TPB, 0, stream>>>(T, S, Btf, tw, valp, R0, out, 1.0f, 0, 0);
        fft_mfma<<<FG, TPB, 0, stream>>>(S, T, Btf, tw, valp, R0, out, 1.0f, 0, 0);
        float2* tmp = S; S = T; T = tmp;
    }
    specmul<<<nb((long)NP*NPIX), TPB, 0, stream>>>(S, Dk, Dgs, T, 1);
    fft_mfma<<<FG, TPB, 0, stream>>>(T, S, Bti, tw, valp, R0, out, isc, 1, 0);
    fft_mfma<<<FG, TPB, 0, stream>>>(S, T, Bti, tw, valp, R0, out, isc, 1, 2);
}

// Round 8
// 1098.179 us; speedup vs baseline: 6.1313x; 1.0392x over previous
//
#include <hip/hip_runtime.h>
#include <cmath>

#define HH 542
#define KH 271
#define NPIX (HH*HH)          // 293764
#define BB 8
#define CC3 3
#define NCH (BB*CC3)          // 24 real channels
#define NP 12                 // 12 packed complex planes
#define MROWS (NP*HH)         // 6504 complex rows per pass
#define KSZ 31
#define KRAD 15
#define NF 8
#define FS 3

#define NSPLIT 3
#define NGRP 40               // 20 re + 20 im groups of 16 v1 (covers 5 bx * 64)
#define BTSZ (NGRP*NSPLIT*17*512)  // shorts per fragment-ordered B-table

typedef __attribute__((ext_vector_type(8))) short short8v;
typedef __attribute__((ext_vector_type(4))) float float4v;

static __device__ __forceinline__ float2 cmul(float2 a, float2 b) {
    return make_float2(a.x*b.x - a.y*b.y, a.x*b.y + a.y*b.x);
}

static __device__ __forceinline__ void pair_chans(int p, int& n1, int& n2) {
    if (p < 8) { n1 = 3*p;     n2 = 3*p + 1; }
    else       { int q = p-8; n1 = 6*q + 2; n2 = 6*q + 5; }
}

// truncation 3-way bf16 split of two adjacent values (x=low short, y=high short)
static __device__ __forceinline__ void split_pack_pair(float x, float y,
        unsigned& p0, unsigned& p1, unsigned& p2) {
    unsigned ux = __float_as_uint(x), uy = __float_as_uint(y);
    unsigned hx0 = ux & 0xffff0000u, hy0 = uy & 0xffff0000u;
    float rx1 = x - __uint_as_float(hx0);
    float ry1 = y - __uint_as_float(hy0);
    unsigned hx1 = __float_as_uint(rx1) & 0xffff0000u;
    unsigned hy1 = __float_as_uint(ry1) & 0xffff0000u;
    float rx2 = rx1 - __uint_as_float(hx1);
    float ry2 = ry1 - __uint_as_float(hy1);
    p0 = (hx0 >> 16) | hy0;
    p1 = (hx1 >> 16) | hy1;
    p2 = (__float_as_uint(rx2) >> 16) | (__float_as_uint(ry2) & 0xffff0000u);
}

// ---------------- tables: tw542 + fragment-ordered split-bf16 B tables (NGRP=40).
// Bt[((g*3+s)*17+step)*512 + lane*8 + j] = split_s of B'[n][k'], n = (g%20)*16+(lane&15)
// (g<20: re-part, g>=20: im-part), k' = step*32 + (lane>>4)*8 + j
__global__ void gen_tables(float2* tw542, short* Btf, short* Bti) {
    int idx = blockIdx.x*blockDim.x + threadIdx.x;
    const float PI2 = 6.283185307179586f;
    if (idx < HH) {
        float ang = -PI2*(float)idx/(float)HH;
        float s, c; sincosf(ang, &s, &c);
        tw542[idx] = make_float2(c, s);
    }
    if (idx >= BTSZ) return;
    int j    = idx & 7;
    int lane = (idx >> 3) & 63;
    int rem  = idx >> 9;
    int step = rem % 17;
    int rem2 = rem / 17;
    int s    = rem2 % 3;
    int g    = rem2 / 3;
    if (g >= NGRP) return;
    int o  = (g >= 20) ? 1 : 0;
    int v1 = (g - 20*o)*16 + (lane & 15);
    int kq = step*32 + (lane >> 4)*8 + j;
    int kidx = kq >> 1, c = kq & 1;
    float wre = 0.f, wim = 0.f;
    if (v1 < KH && kidx < KH) {
        int r = (kidx*v1) % KH;
        float ang = -PI2*(float)r/(float)KH;
        float sn, cs; sincosf(ang, &sn, &cs);
        wre = cs; wim = sn;
    }
    float vf = (o==0) ? ((c==0) ? wre : -wim) : ((c==0) ?  wim : wre);
    float vi = (o==0) ? ((c==0) ? wre :  wim) : ((c==0) ? -wim : wre);
    {
        unsigned u = __float_as_uint(vf);
        unsigned h0 = u & 0xffff0000u;
        float r1 = vf - __uint_as_float(h0);
        unsigned h1 = __float_as_uint(r1) & 0xffff0000u;
        float r2 = r1 - __uint_as_float(h1);
        unsigned sp = (s==0) ? h0 : (s==1) ? h1 : (__float_as_uint(r2) & 0xffff0000u);
        Btf[idx] = (short)(sp >> 16);
    }
    {
        unsigned u = __float_as_uint(vi);
        unsigned h0 = u & 0xffff0000u;
        float r1 = vi - __uint_as_float(h0);
        unsigned h1 = __float_as_uint(r1) & 0xffff0000u;
        float r2 = r1 - __uint_as_float(h1);
        unsigned sp = (s==0) ? h0 : (s==1) ? h1 : (__float_as_uint(r2) & 0xffff0000u);
        Bti[idx] = (short)(sp >> 16);
    }
}

// ---------------- edgetaper alpha vectors (closed-form autocorrelation)
__global__ void alpha_kernel(const float* __restrict__ kk, float* __restrict__ valpha) {
    int b = blockIdx.x;
    int t = threadIdx.x;
    __shared__ float proj[2][KSZ];
    __shared__ float ac[2][KSZ];
    const float* kb = kk + b*KSZ*KSZ;
    if (t < KSZ) {
        float s = 0;
        for (int j = 0; j < KSZ; j++) s += kb[t*KSZ + j];
        proj[0][t] = s;
    } else if (t >= 32 && t < 32+KSZ) {
        int j = t - 32;
        float s = 0;
        for (int i = 0; i < KSZ; i++) s += kb[i*KSZ + j];
        proj[1][j] = s;
    }
    __syncthreads();
    if (t < KSZ) {
        float s0 = 0, s1 = 0;
        for (int m = 0; m + t < KSZ; m++) {
            s0 += proj[0][m]*proj[0][m+t];
            s1 += proj[1][m]*proj[1][m+t];
        }
        ac[0][t] = s0; ac[1][t] = s1;
    }
    __syncthreads();
    float inv0 = 1.0f/ac[0][0];
    float inv1 = 1.0f/ac[1][0];
    for (int d = t; d < HH; d += blockDim.x) {
        for (int a = 0; a < 2; a++) {
            float z;
            if (d <= 30)                   z = ac[a][d];
            else if (d >= 511 && d <= 540) z = ac[a][541-d];
            else if (d == 541)             z = ac[a][0];
            else                           z = 0.0f;
            valpha[(b*2 + a)*HH + d] = 1.0f - z*(a ? inv1 : inv0);
        }
    }
}

// ---------------- Dk = psf2otf(k) via two small DFT stages (mod-free indexing)
__global__ void dk_stage1(const float* __restrict__ kk, const float2* __restrict__ tw,
                          float2* __restrict__ T1) {
    int idx = blockIdx.x*blockDim.x + threadIdx.x;
    if (idx >= BB*KSZ*HH) return;
    int v  = idx % HH;
    int bm = idx / HH;
    int m  = bm % KSZ;
    int b  = bm / KSZ;
    const float* kb = kk + (b*KSZ + m)*KSZ;
    float2 acc = make_float2(0.f, 0.f);
    int r = (KRAD*(HH - v)) % HH;
    for (int n = 0; n < KSZ; n++) {
        float2 w = tw[r];
        float kv = kb[n];
        acc.x = fmaf(kv, w.x, acc.x);
        acc.y = fmaf(kv, w.y, acc.y);
        r += v; if (r >= HH) r -= HH;
    }
    T1[idx] = acc;
}

// 4 rotating accumulators -> 4x ILP on the FMA-latency-bound reduction chain
__global__ void dk_stage2(const float2* __restrict__ T1, const float2* __restrict__ tw,
                          float2* __restrict__ Dk) {
    int idx = blockIdx.x*blockDim.x + threadIdx.x;
    if (idx >= BB*NPIX) return;
    int uv = idx % NPIX;
    int b  = idx / NPIX;
    int u  = uv / HH;
    int v  = uv - u*HH;
    float2 acc4[4];
    #pragma unroll
    for (int a = 0; a < 4; a++) acc4[a] = make_float2(0.f, 0.f);
    int r = (KRAD*(HH - u)) % HH;
    const float2* t1 = T1 + (size_t)b*KSZ*HH + v;
    #pragma unroll 4
    for (int m = 0; m < KSZ; m++) {
        float2 w = tw[r];
        float2 t = t1[(size_t)m*HH];
        int a = m & 3;
        acc4[a].x = fmaf(t.x, w.x, fmaf(-t.y, w.y, acc4[a].x));
        acc4[a].y = fmaf(t.x, w.y, fmaf( t.y, w.x, acc4[a].y));
        r += u; if (r >= HH) r -= HH;
    }
    float2 acc = make_float2(acc4[0].x + acc4[1].x + acc4[2].x + acc4[3].x,
                             acc4[0].y + acc4[1].y + acc4[2].y + acc4[3].y);
    Dk[idx] = acc;
}

// ---------------- Dg_sum[c][u][v] = exp(lam)*sum_f |DFT(filt[f,c])|^2 (mod-free)
__global__ void dgs_kernel(const float* __restrict__ filt, const float* __restrict__ lamp,
                           const float2* __restrict__ tw, float* __restrict__ Dgs) {
    int uv = blockIdx.x*blockDim.x + threadIdx.x;
    if (uv >= NPIX) return;
    int u = uv / HH;
    int v = uv - u*HH;
    float el = expf(lamp[0]);
    float2 wu[3], wv[3];
    wu[0] = tw[u ? HH-u : 0]; wu[1] = make_float2(1.f,0.f); wu[2] = tw[u];
    wv[0] = tw[v ? HH-v : 0]; wv[1] = make_float2(1.f,0.f); wv[2] = tw[v];
    float2 ph[3][3];
    #pragma unroll
    for (int m = 0; m < 3; m++)
        #pragma unroll
        for (int n = 0; n < 3; n++)
            ph[m][n] = cmul(wu[m], wv[n]);
    for (int c = 0; c < CC3; c++) {
        float s = 0.f;
        for (int f = 0; f < NF; f++) {
            float2 acc = make_float2(0.f, 0.f);
            const float* fp = filt + ((f*CC3 + c)*FS)*FS;
            #pragma unroll
            for (int m = 0; m < 3; m++)
                #pragma unroll
                for (int n = 0; n < 3; n++) {
                    float fv = fp[m*3+n];
                    acc.x = fmaf(fv, ph[m][n].x, acc.x);
                    acc.y = fmaf(fv, ph[m][n].y, acc.y);
                }
            s = fmaf(acc.x, acc.x, fmaf(acc.y, acc.y, s));
        }
        Dgs[c*NPIX + uv] = s*el;
    }
}

// ---------------- edge-replicate pad + pack pairs
__global__ void pad_pack(const float* __restrict__ y, float* __restrict__ R0,
                         float2* __restrict__ CA) {
    int idx = blockIdx.x*blockDim.x + threadIdx.x;
    if (idx >= NP*NPIX) return;
    int uv = idx % NPIX;
    int p  = idx / NPIX;
    int n1, n2; pair_chans(p, n1, n2);
    int i = uv / HH, j = uv - i*HH;
    int yi = min(max(i - KRAD, 0), 511);
    int yj = min(max(j - KRAD, 0), 511);
    int yo = yi*512 + yj;
    float v1 = y[(size_t)n1*262144 + yo];
    float v2 = y[(size_t)n2*262144 + yo];
    R0[(size_t)n1*NPIX + uv] = v1;
    R0[(size_t)n2*NPIX + uv] = v2;
    CA[idx] = make_float2(v1, v2);
}

// ---------------- Hermitian unpack, per-channel multiply, repack.
__global__ void specmul(const float2* __restrict__ CA, const float2* __restrict__ Dk,
                        const float* __restrict__ Dgs, float2* __restrict__ CB, int mode) {
    int idx = blockIdx.x*blockDim.x + threadIdx.x;
    if (idx >= NP*NPIX) return;
    int uv = idx % NPIX;
    int p  = idx / NPIX;
    int n1, n2; pair_chans(p, n1, n2);
    int b1 = n1/3, c1 = n1 - 3*b1;
    int b2 = n2/3, c2 = n2 - 3*b2;
    int i = uv / HH, j = uv - i*HH;
    int ni = i ? HH - i : 0;
    int nj = j ? HH - j : 0;
    float2 Z  = CA[(size_t)p*NPIX + uv];
    float2 Zm = CA[(size_t)p*NPIX + ni*HH + nj];
    float2 F1 = make_float2(0.5f*(Z.x + Zm.x), 0.5f*(Z.y - Zm.y));
    float2 F2 = make_float2(0.5f*(Z.y + Zm.y), 0.5f*(Zm.x - Z.x));
    float2 d1 = Dk[(size_t)b1*NPIX + uv];
    float2 d2 = Dk[(size_t)b2*NPIX + uv];
    float2 M1, M2;
    if (mode == 0) {
        M1 = d1; M2 = d2;
    } else {
        float o1 = 1.0f/(d1.x*d1.x + d1.y*d1.y + Dgs[(size_t)c1*NPIX + uv]);
        float o2 = 1.0f/(d2.x*d2.x + d2.y*d2.y + Dgs[(size_t)c2*NPIX + uv]);
        M1 = make_float2(d1.x*o1, -d1.y*o1);
        M2 = make_float2(d2.x*o2, -d2.y*o2);
    }
    float2 W1 = cmul(M1, F1);
    float2 W2 = cmul(M2, F2);
    CB[idx] = make_float2(W1.x - W2.y, W1.y + W2.x);
}

// ---------------- MFMA DFT pass, wide-N: block = 128 A'rows x 64 v1, 4 waves,
// each wave 64 A'rows x 32 v1 (mt=4 x ct=4), 96 MFMA per K-step vs 12 ds_read.
// A staged+split in LDS; B fragments direct from L2 table; epilogue transposes
// through LDS with wave-contiguous float4 stores; optional fused blend/out.
// mode: 0 = plain transposed write, 1 = fused edgetaper blend, 2 = final out
__global__ void __launch_bounds__(256, 2)
fft_mfma(const float2* __restrict__ Ain, float2* __restrict__ Aout,
         const short* __restrict__ Bt, const float2* __restrict__ tw542,
         const float* __restrict__ valp, float* __restrict__ R0,
         float* __restrict__ outbuf, float scale, int conjtw, int mode)
{
    __shared__ char smem[34048];          // staging 30720 B; Ts 64x66 float2 = 33792 B
    short* As = (short*)smem;
    float2* Ts = (float2*)smem;
    const int APL = 128*40;

    // XCD-locality swizzle: 510 active blocks, ~64 consecutive lin per XCD
    int id = blockIdx.x;
    int xcd = id & 7, jj = id >> 3;
    int lin = xcd*64 + jj;
    if (lin >= 510) return;
    int by = lin / 5, bx = lin - 5*by;

    int tid = threadIdx.x;
    int arow = tid >> 3, ai4 = tid & 7;
    int wid = tid >> 6, lane = tid & 63;
    int wxm = wid & 1, wy = wid >> 1;
    int l15 = lane & 15, quad = lane >> 4;

    int aoff0 = (wxm*64 + l15)*40 + quad*8;

    const short* pB[4];
    #pragma unroll
    for (int ct = 0; ct < 4; ct++) {
        int g = ct >> 1, im = ct & 1;
        int grp = (im ? 20 : 0) + bx*4 + wy*2 + g;
        pB[ct] = Bt + (size_t)grp*(3*17*512) + lane*8;
    }

    float4v acc[4][4];   // [mt][ct]
    #pragma unroll
    for (int mt = 0; mt < 4; mt++)
        #pragma unroll
        for (int ct = 0; ct < 4; ct++)
            acc[mt][ct] = (float4v)(0.f);

    float4 regA[2][2][2];        // [buf][qq][pair]
    short8v bf[2][4][3];         // [buf][ct][split]
    const float4 z4 = make_float4(0.f,0.f,0.f,0.f);

    auto loadA = [&](int buf, int step) {
        #pragma unroll
        for (int qq = 0; qq < 2; qq++) {
            int rowg = by*64 + arow + 32*qq;
            bool rvld = rowg < MROWS;
            const float4* rp = (const float4*)Ain + (size_t)(rvld ? rowg : 0)*271;
            int i0 = step*16 + 2*ai4;
            regA[buf][qq][0] = (rvld && i0     < 271) ? rp[i0]   : z4;
            regA[buf][qq][1] = (rvld && i0 + 1 < 271) ? rp[i0+1] : z4;
        }
    };
    auto loadB = [&](int buf, int step) {
        #pragma unroll
        for (int ct = 0; ct < 4; ct++)
            #pragma unroll
            for (int s = 0; s < 3; s++)
                bf[buf][ct][s] = *(const short8v*)(pB[ct] + ((s*17 + step) << 9));
    };

    loadA(0, 0); loadB(0, 0);

    #pragma unroll 2
    for (int step = 0; step < 17; step++) {
        int cur = step & 1, nxt = cur ^ 1;
        // stage A tile into LDS with 3-way bf16 split
        #pragma unroll
        for (int qq = 0; qq < 2; qq++) {
            int rl = 2*(arow + 32*qq);
            int offE = rl*40 + 4*ai4;
            float4 f0 = regA[cur][qq][0], f1 = regA[cur][qq][1];
            unsigned e0a,e1a,e2a, e0b,e1b,e2b;
            split_pack_pair(f0.x, f0.y, e0a, e1a, e2a);
            split_pack_pair(f1.x, f1.y, e0b, e1b, e2b);
            *(uint2*)(As + 0*APL + offE) = make_uint2(e0a, e0b);
            *(uint2*)(As + 1*APL + offE) = make_uint2(e1a, e1b);
            *(uint2*)(As + 2*APL + offE) = make_uint2(e2a, e2b);
            unsigned o0a,o1a,o2a, o0b,o1b,o2b;
            split_pack_pair(f0.z, f0.w, o0a, o1a, o2a);
            split_pack_pair(f1.z, f1.w, o0b, o1b, o2b);
            int offO = offE + 40;
            *(uint2*)(As + 0*APL + offO) = make_uint2(o0a, o0b);
            *(uint2*)(As + 1*APL + offO) = make_uint2(o1a, o1b);
            *(uint2*)(As + 2*APL + offO) = make_uint2(o2a, o2b);
        }
        __syncthreads();

        if (step + 1 < 17) { loadA(nxt, step+1); loadB(nxt, step+1); }

        #pragma unroll
        for (int sa = 0; sa < 3; sa++) {
            short8v af[4];
            #pragma unroll
            for (int mt = 0; mt < 4; mt++)
                af[mt] = *(const short8v*)(As + sa*APL + aoff0 + mt*16*40);
            #pragma unroll
            for (int sb = 0; sb + sa < 3; sb++)
                #pragma unroll
                for (int mt = 0; mt < 4; mt++)
                    #pragma unroll
                    for (int ct = 0; ct < 4; ct++)
                        acc[mt][ct] = __builtin_amdgcn_mfma_f32_16x16x32_bf16(
                            af[mt], bf[cur][ct][sb], acc[mt][ct], 0, 0, 0);
        }
        __syncthreads();
    }

    // ---- epilogue: twiddle combine, LDS transpose (64v1 x 64cols), coalesced writes
    float2 tg[2];
    #pragma unroll
    for (int g = 0; g < 2; g++) {
        int v1g = (bx*4 + wy*2 + g)*16 + l15;
        tg[g] = tw542[(v1g < HH) ? v1g : 0];
        if (conjtw) tg[g].y = -tg[g].y;
    }

    int lanec = tid & 31;
    int c0 = lanec*2;
    int r0g = by*64 + c0;                 // even complex col; float4 never straddles plane
    bool rok = r0g < MROWS;
    int plane = rok ? (r0g / HH) : 0;
    int colg = r0g - plane*HH;
    int n1, n2; pair_chans(plane, n1, n2);
    int b1 = n1/3, b2 = n2/3;

    #pragma unroll
    for (int half = 0; half < 2; half++) {
        __syncthreads();
        #pragma unroll
        for (int mt = 0; mt < 4; mt++) {
            #pragma unroll
            for (int g = 0; g < 2; g++) {
                #pragma unroll
                for (int pr = 0; pr < 2; pr++) {
                    float Ere = acc[mt][g*2  ][2*pr], Ore = acc[mt][g*2  ][2*pr+1];
                    float Eim = acc[mt][g*2+1][2*pr], Oim = acc[mt][g*2+1][2*pr+1];
                    float tOre = tg[g].x*Ore - tg[g].y*Oim;
                    float tOim = tg[g].x*Oim + tg[g].y*Ore;
                    int v1loc = (wy*2 + g)*16 + l15;
                    int cloc = wxm*32 + mt*8 + quad*2 + pr;
                    float2 v = (half == 0)
                        ? make_float2((Ere + tOre)*scale, (Eim + tOim)*scale)
                        : make_float2((Ere - tOre)*scale, (Eim - tOim)*scale);
                    Ts[v1loc*66 + cloc] = v;
                }
            }
        }
        __syncthreads();
        #pragma unroll
        for (int it = 0; it < 8; it++) {
            int v1loc = (tid >> 5) + it*8;
            int v1g = bx*64 + v1loc;
            if (v1g >= KH || !rok) continue;
            int v1 = v1g + (half ? KH : 0);
            float2 a0 = Ts[v1loc*66 + c0];
            float2 a1 = Ts[v1loc*66 + c0 + 1];
            size_t sp = (size_t)v1*HH + colg;
            if (mode == 0) {
                *(float4*)(Aout + (size_t)plane*NPIX + sp) =
                    make_float4(a0.x, a0.y, a1.x, a1.y);
            } else if (mode == 1) {
                float ar1 = valp[b1*2*HH + v1];
                float ar2 = valp[b2*2*HH + v1];
                float ac1a = valp[(b1*2+1)*HH + colg];
                float ac1b = valp[(b1*2+1)*HH + colg + 1];
                float ac2a = valp[(b2*2+1)*HH + colg];
                float ac2b = valp[(b2*2+1)*HH + colg + 1];
                float2* p1 = (float2*)(R0 + (size_t)n1*NPIX + sp);
                float2* p2 = (float2*)(R0 + (size_t)n2*NPIX + sp);
                float2 o1 = *p1, o2 = *p2;
                float nv1a = fmaf(ar1*ac1a, o1.x - a0.x, a0.x);
                float nv1b = fmaf(ar1*ac1b, o1.y - a1.x, a1.x);
                float nv2a = fmaf(ar2*ac2a, o2.x - a0.y, a0.y);
                float nv2b = fmaf(ar2*ac2b, o2.y - a1.y, a1.y);
                *p1 = make_float2(nv1a, nv1b);
                *p2 = make_float2(nv2a, nv2b);
                *(float4*)(Aout + (size_t)plane*NPIX + sp) =
                    make_float4(nv1a, nv2a, nv1b, nv2b);
            } else {
                *(float2*)(outbuf + (size_t)n1*NPIX + sp) = make_float2(a0.x, a1.x);
                *(float2*)(outbuf + (size_t)n2*NPIX + sp) = make_float2(a0.y, a1.y);
            }
        }
    }
}

extern "C" void kernel_launch(void* const* d_in, const int* in_sizes, int n_in,
                              void* d_out, int out_size, void* d_ws, size_t ws_size,
                              hipStream_t stream) {
    const float* y    = (const float*)d_in[0];
    const float* k    = (const float*)d_in[1];
    const float* lam  = (const float*)d_in[2];
    const float* filt = (const float*)d_in[3];
    float* out = (float*)d_out;

    char* base = (char*)d_ws;
    size_t off = 0;
    auto alloc = [&](size_t bytes) {
        void* p = base + off;
        off = (off + bytes + 511) & ~(size_t)511;
        return p;
    };
    float2* CA   = (float2*)alloc(sizeof(float2)*(size_t)NP*NPIX);
    float2* CB   = (float2*)alloc(sizeof(float2)*(size_t)NP*NPIX);
    float*  R0   = (float*) alloc(sizeof(float)*(size_t)NCH*NPIX);
    float2* Dk   = (float2*)alloc(sizeof(float2)*(size_t)BB*NPIX);
    float2* T1   = (float2*)alloc(sizeof(float2)*(size_t)BB*KSZ*HH);
    float*  Dgs  = (float*) alloc(sizeof(float)*(size_t)CC3*NPIX);
    short*  Btf  = (short*) alloc(sizeof(short)*(size_t)BTSZ);
    short*  Bti  = (short*) alloc(sizeof(short)*(size_t)BTSZ);
    float2* tw   = (float2*)alloc(sizeof(float2)*(size_t)HH);
    float*  valp = (float*) alloc(sizeof(float)*(size_t)BB*2*HH);
    (void)ws_size; (void)in_sizes; (void)n_in; (void)out_size;

    const int TPB = 256;
    auto nb = [](long n) { return (int)((n + 255)/256); };

    gen_tables<<<nb((long)BTSZ), TPB, 0, stream>>>(tw, Btf, Bti);
    alpha_kernel<<<BB, 64, 0, stream>>>(k, valp);
    dk_stage1<<<nb((long)BB*KSZ*HH), TPB, 0, stream>>>(k, tw, T1);
    dk_stage2<<<nb((long)BB*NPIX), TPB, 0, stream>>>(T1, tw, Dk);
    dgs_kernel<<<nb((long)NPIX), TPB, 0, stream>>>(filt, lam, tw, Dgs);
    pad_pack<<<nb((long)NP*NPIX), TPB, 0, stream>>>(y, R0, CA);

    const int FG = 512;   // 8 XCDs x 64 (510 active)
    const float isc = 1.0f/(float)HH;
    float2 *S = CA, *T = CB;
    fft_mfma<<<FG, TPB, 0, stream>>>(S, T, Btf, tw, valp, R0, out, 1.0f, 0, 0);
    fft_mfma<<<FG, TPB, 0, stream>>>(T, S, Btf, tw, valp, R0, out, 1.0f, 0, 0);
    for (int it = 0; it < 3; it++) {
        specmul<<<nb((long)NP*NPIX), TPB, 0, stream>>>(S, Dk, Dgs, T, 0);
        fft_mfma<<<FG, TPB, 0, stream>>>(T, S, Bti, tw, valp, R0, out, isc, 1, 0);
        fft_mfma<<<FG, TPB, 0, stream>>>(S, T, Bti, tw, valp, R0, out, isc, 1, 1);
        fft_mfma<<<FG, TPB, 0, stream>>>(T, S, Btf, tw, valp, R0, out, 1.0f, 0, 0);
        fft_mfma<<<FG, TPB, 0, stream>>>(S, T, Btf, tw, valp, R0, out, 1.0f, 0, 0);
        float2* tmp = S; S = T; T = tmp;
    }
    specmul<<<nb((long)NP*NPIX), TPB, 0, stream>>>(S, Dk, Dgs, T, 1);
    fft_mfma<<<FG, TPB, 0, stream>>>(T, S, Bti, tw, valp, R0, out, isc, 1, 0);
    fft_mfma<<<FG, TPB, 0, stream>>>(S, T, Bti, tw, valp, R0, out, isc, 1, 2);
}

// Round 9
// 857.272 us; speedup vs baseline: 7.8542x; 1.2810x over previous
//
#include <hip/hip_runtime.h>
#include <cmath>

#define HH 542
#define KH 271
#define NPIX (HH*HH)          // 293764
#define BB 8
#define CC3 3
#define NCH (BB*CC3)          // 24 real channels
#define NP 12                 // 12 packed complex planes
#define MROWS (NP*HH)         // 6504 complex rows per pass
#define KSZ 31
#define KRAD 15
#define NF 8
#define FS 3

#define NSPLIT 2
#define NGRP 40               // 20 re + 20 im groups of 16 v1
#define BTSZ (NGRP*NSPLIT*17*512)  // shorts per fragment-ordered B-table

typedef __attribute__((ext_vector_type(8))) short short8v;
typedef __attribute__((ext_vector_type(4))) float float4v;

static __device__ __forceinline__ float2 cmul(float2 a, float2 b) {
    return make_float2(a.x*b.x - a.y*b.y, a.x*b.y + a.y*b.x);
}

static __device__ __forceinline__ void pair_chans(int p, int& n1, int& n2) {
    if (p < 8) { n1 = 3*p;     n2 = 3*p + 1; }
    else       { int q = p-8; n1 = 6*q + 2; n2 = 6*q + 5; }
}

// ROUNDED 2-way bf16 split of two adjacent values (x=low short, y=high short).
// round-half-away via +0x8000 before truncate; residual <= 2^-18 relative.
static __device__ __forceinline__ void split2_pack_pair(float x, float y,
        unsigned& p0, unsigned& p1) {
    unsigned ux = __float_as_uint(x), uy = __float_as_uint(y);
    unsigned hx0 = (ux + 0x8000u) & 0xffff0000u;
    unsigned hy0 = (uy + 0x8000u) & 0xffff0000u;
    float rx = x - __uint_as_float(hx0);
    float ry = y - __uint_as_float(hy0);
    unsigned hx1 = (__float_as_uint(rx) + 0x8000u) & 0xffff0000u;
    unsigned hy1 = (__float_as_uint(ry) + 0x8000u) & 0xffff0000u;
    p0 = (hx0 >> 16) | hy0;
    p1 = (hx1 >> 16) | hy1;
}

// ---------------- tables: tw542 + fragment-ordered rounded-2-split bf16 B tables.
// Bt[((g*2+s)*17+step)*512 + lane*8 + j] = split_s of B'[n][k'], n=(g%20)*16+(lane&15)
// (g<20: re-part, g>=20: im-part), k' = step*32 + (lane>>4)*8 + j
__global__ void gen_tables(float2* tw542, short* Btf, short* Bti) {
    int idx = blockIdx.x*blockDim.x + threadIdx.x;
    const float PI2 = 6.283185307179586f;
    if (idx < HH) {
        float ang = -PI2*(float)idx/(float)HH;
        float s, c; sincosf(ang, &s, &c);
        tw542[idx] = make_float2(c, s);
    }
    if (idx >= BTSZ) return;
    int j    = idx & 7;
    int lane = (idx >> 3) & 63;
    int rem  = idx >> 9;
    int step = rem % 17;
    int rem2 = rem / 17;
    int s    = rem2 % NSPLIT;
    int g    = rem2 / NSPLIT;
    if (g >= NGRP) return;
    int o  = (g >= 20) ? 1 : 0;
    int v1 = (g - 20*o)*16 + (lane & 15);
    int kq = step*32 + (lane >> 4)*8 + j;
    int kidx = kq >> 1, c = kq & 1;
    float wre = 0.f, wim = 0.f;
    if (v1 < KH && kidx < KH) {
        int r = (kidx*v1) % KH;
        float ang = -PI2*(float)r/(float)KH;
        float sn, cs; sincosf(ang, &sn, &cs);
        wre = cs; wim = sn;
    }
    float vf = (o==0) ? ((c==0) ? wre : -wim) : ((c==0) ?  wim : wre);
    float vi = (o==0) ? ((c==0) ? wre :  wim) : ((c==0) ? -wim : wre);
    {
        unsigned u = __float_as_uint(vf);
        unsigned h0 = (u + 0x8000u) & 0xffff0000u;
        float r1 = vf - __uint_as_float(h0);
        unsigned h1 = (__float_as_uint(r1) + 0x8000u) & 0xffff0000u;
        Btf[idx] = (short)(((s==0) ? h0 : h1) >> 16);
    }
    {
        unsigned u = __float_as_uint(vi);
        unsigned h0 = (u + 0x8000u) & 0xffff0000u;
        float r1 = vi - __uint_as_float(h0);
        unsigned h1 = (__float_as_uint(r1) + 0x8000u) & 0xffff0000u;
        Bti[idx] = (short)(((s==0) ? h0 : h1) >> 16);
    }
}

// ---------------- edgetaper alpha vectors (closed-form autocorrelation)
__global__ void alpha_kernel(const float* __restrict__ kk, float* __restrict__ valpha) {
    int b = blockIdx.x;
    int t = threadIdx.x;
    __shared__ float proj[2][KSZ];
    __shared__ float ac[2][KSZ];
    const float* kb = kk + b*KSZ*KSZ;
    if (t < KSZ) {
        float s = 0;
        for (int j = 0; j < KSZ; j++) s += kb[t*KSZ + j];
        proj[0][t] = s;
    } else if (t >= 32 && t < 32+KSZ) {
        int j = t - 32;
        float s = 0;
        for (int i = 0; i < KSZ; i++) s += kb[i*KSZ + j];
        proj[1][j] = s;
    }
    __syncthreads();
    if (t < KSZ) {
        float s0 = 0, s1 = 0;
        for (int m = 0; m + t < KSZ; m++) {
            s0 += proj[0][m]*proj[0][m+t];
            s1 += proj[1][m]*proj[1][m+t];
        }
        ac[0][t] = s0; ac[1][t] = s1;
    }
    __syncthreads();
    float inv0 = 1.0f/ac[0][0];
    float inv1 = 1.0f/ac[1][0];
    for (int d = t; d < HH; d += blockDim.x) {
        for (int a = 0; a < 2; a++) {
            float z;
            if (d <= 30)                   z = ac[a][d];
            else if (d >= 511 && d <= 540) z = ac[a][541-d];
            else if (d == 541)             z = ac[a][0];
            else                           z = 0.0f;
            valpha[(b*2 + a)*HH + d] = 1.0f - z*(a ? inv1 : inv0);
        }
    }
}

// ---------------- Dk = psf2otf(k) via two small DFT stages (mod-free indexing)
__global__ void dk_stage1(const float* __restrict__ kk, const float2* __restrict__ tw,
                          float2* __restrict__ T1) {
    int idx = blockIdx.x*blockDim.x + threadIdx.x;
    if (idx >= BB*KSZ*HH) return;
    int v  = idx % HH;
    int bm = idx / HH;
    int m  = bm % KSZ;
    int b  = bm / KSZ;
    const float* kb = kk + (b*KSZ + m)*KSZ;
    float2 acc = make_float2(0.f, 0.f);
    int r = (KRAD*(HH - v)) % HH;
    for (int n = 0; n < KSZ; n++) {
        float2 w = tw[r];
        float kv = kb[n];
        acc.x = fmaf(kv, w.x, acc.x);
        acc.y = fmaf(kv, w.y, acc.y);
        r += v; if (r >= HH) r -= HH;
    }
    T1[idx] = acc;
}

// T1 reuse across u: thread = (b, v, 4-u tile); each T1 load feeds 4 outputs.
// grid = b(8) x ut(136) x vchunk(3), block 256 (thread = v within chunk)
__global__ void dk_stage2(const float2* __restrict__ T1, const float2* __restrict__ tw,
                          float2* __restrict__ Dk) {
    int bid = blockIdx.x;
    int vc = bid % 3;
    int rem = bid / 3;
    int ut = rem % 136;
    int b  = rem / 136;
    int v = vc*256 + threadIdx.x;
    if (v >= HH) return;
    int u0 = ut*4;
    float2 acc[4];
    int r[4];
    #pragma unroll
    for (int uu = 0; uu < 4; uu++) {
        acc[uu] = make_float2(0.f, 0.f);
        int u = u0 + uu;
        r[uu] = (u < HH) ? (KRAD*(HH - u)) % HH : 0;
    }
    const float2* t1 = T1 + (size_t)b*KSZ*HH + v;
    for (int m = 0; m < KSZ; m++) {
        float2 t = t1[(size_t)m*HH];
        #pragma unroll
        for (int uu = 0; uu < 4; uu++) {
            float2 w = tw[r[uu]];
            acc[uu].x = fmaf(t.x, w.x, fmaf(-t.y, w.y, acc[uu].x));
            acc[uu].y = fmaf(t.x, w.y, fmaf( t.y, w.x, acc[uu].y));
            int rn = r[uu] + u0 + uu;
            r[uu] = (rn >= HH) ? rn - HH : rn;
        }
    }
    #pragma unroll
    for (int uu = 0; uu < 4; uu++) {
        int u = u0 + uu;
        if (u < HH) Dk[(size_t)b*NPIX + (size_t)u*HH + v] = acc[uu];
    }
}

// ---------------- Dg_sum[c][u][v] = exp(lam)*sum_f |DFT(filt[f,c])|^2 (mod-free)
__global__ void dgs_kernel(const float* __restrict__ filt, const float* __restrict__ lamp,
                           const float2* __restrict__ tw, float* __restrict__ Dgs) {
    int uv = blockIdx.x*blockDim.x + threadIdx.x;
    if (uv >= NPIX) return;
    int u = uv / HH;
    int v = uv - u*HH;
    float el = expf(lamp[0]);
    float2 wu[3], wv[3];
    wu[0] = tw[u ? HH-u : 0]; wu[1] = make_float2(1.f,0.f); wu[2] = tw[u];
    wv[0] = tw[v ? HH-v : 0]; wv[1] = make_float2(1.f,0.f); wv[2] = tw[v];
    float2 ph[3][3];
    #pragma unroll
    for (int m = 0; m < 3; m++)
        #pragma unroll
        for (int n = 0; n < 3; n++)
            ph[m][n] = cmul(wu[m], wv[n]);
    for (int c = 0; c < CC3; c++) {
        float s = 0.f;
        for (int f = 0; f < NF; f++) {
            float2 acc = make_float2(0.f, 0.f);
            const float* fp = filt + ((f*CC3 + c)*FS)*FS;
            #pragma unroll
            for (int m = 0; m < 3; m++)
                #pragma unroll
                for (int n = 0; n < 3; n++) {
                    float fv = fp[m*3+n];
                    acc.x = fmaf(fv, ph[m][n].x, acc.x);
                    acc.y = fmaf(fv, ph[m][n].y, acc.y);
                }
            s = fmaf(acc.x, acc.x, fmaf(acc.y, acc.y, s));
        }
        Dgs[c*NPIX + uv] = s*el;
    }
}

// ---------------- edge-replicate pad + pack pairs
__global__ void pad_pack(const float* __restrict__ y, float* __restrict__ R0,
                         float2* __restrict__ CA) {
    int idx = blockIdx.x*blockDim.x + threadIdx.x;
    if (idx >= NP*NPIX) return;
    int uv = idx % NPIX;
    int p  = idx / NPIX;
    int n1, n2; pair_chans(p, n1, n2);
    int i = uv / HH, j = uv - i*HH;
    int yi = min(max(i - KRAD, 0), 511);
    int yj = min(max(j - KRAD, 0), 511);
    int yo = yi*512 + yj;
    float v1 = y[(size_t)n1*262144 + yo];
    float v2 = y[(size_t)n2*262144 + yo];
    R0[(size_t)n1*NPIX + uv] = v1;
    R0[(size_t)n2*NPIX + uv] = v2;
    CA[idx] = make_float2(v1, v2);
}

// ---------------- Hermitian unpack, per-channel multiply, repack.
__global__ void specmul(const float2* __restrict__ CA, const float2* __restrict__ Dk,
                        const float* __restrict__ Dgs, float2* __restrict__ CB, int mode) {
    int idx = blockIdx.x*blockDim.x + threadIdx.x;
    if (idx >= NP*NPIX) return;
    int uv = idx % NPIX;
    int p  = idx / NPIX;
    int n1, n2; pair_chans(p, n1, n2);
    int b1 = n1/3, c1 = n1 - 3*b1;
    int b2 = n2/3, c2 = n2 - 3*b2;
    int i = uv / HH, j = uv - i*HH;
    int ni = i ? HH - i : 0;
    int nj = j ? HH - j : 0;
    float2 Z  = CA[(size_t)p*NPIX + uv];
    float2 Zm = CA[(size_t)p*NPIX + ni*HH + nj];
    float2 F1 = make_float2(0.5f*(Z.x + Zm.x), 0.5f*(Z.y - Zm.y));
    float2 F2 = make_float2(0.5f*(Z.y + Zm.y), 0.5f*(Zm.x - Z.x));
    float2 d1 = Dk[(size_t)b1*NPIX + uv];
    float2 d2 = Dk[(size_t)b2*NPIX + uv];
    float2 M1, M2;
    if (mode == 0) {
        M1 = d1; M2 = d2;
    } else {
        float o1 = 1.0f/(d1.x*d1.x + d1.y*d1.y + Dgs[(size_t)c1*NPIX + uv]);
        float o2 = 1.0f/(d2.x*d2.x + d2.y*d2.y + Dgs[(size_t)c2*NPIX + uv]);
        M1 = make_float2(d1.x*o1, -d1.y*o1);
        M2 = make_float2(d2.x*o2, -d2.y*o2);
    }
    float2 W1 = cmul(M1, F1);
    float2 W2 = cmul(M2, F2);
    CB[idx] = make_float2(W1.x - W2.y, W1.y + W2.x);
}

// ---------------- MFMA DFT pass: rounded-2-split, 3 products, wide-N.
// block = 128 A'rows x 64 v1, 4 waves, each 64 A'rows x 32 v1 (mt4 x ct4),
// 48 MFMA vs 8 ds_read per K-step. Epilogue: twiddle + LDS transpose +
// wave-contiguous float4 stores; optional fused blend (1) / final out (2).
__global__ void __launch_bounds__(256, 2)
fft_mfma(const float2* __restrict__ Ain, float2* __restrict__ Aout,
         const short* __restrict__ Bt, const float2* __restrict__ tw542,
         const float* __restrict__ valp, float* __restrict__ R0,
         float* __restrict__ outbuf, float scale, int conjtw, int mode)
{
    __shared__ char smem[33792];          // staging 20480 B; Ts 64x66 float2 = 33792 B
    short* As = (short*)smem;
    float2* Ts = (float2*)smem;
    const int APL = 128*40;

    int id = blockIdx.x;
    int xcd = id & 7, jj = id >> 3;
    int lin = xcd*64 + jj;
    if (lin >= 510) return;
    int by = lin / 5, bx = lin - 5*by;

    int tid = threadIdx.x;
    int arow = tid >> 3, ai4 = tid & 7;
    int wid = tid >> 6, lane = tid & 63;
    int wxm = wid & 1, wy = wid >> 1;
    int l15 = lane & 15, quad = lane >> 4;

    int aoff0 = (wxm*64 + l15)*40 + quad*8;

    const short* pB[4];
    #pragma unroll
    for (int ct = 0; ct < 4; ct++) {
        int g = ct >> 1, im = ct & 1;
        int grp = (im ? 20 : 0) + bx*4 + wy*2 + g;
        pB[ct] = Bt + (size_t)grp*(NSPLIT*17*512) + lane*8;
    }

    float4v acc[4][4];   // [mt][ct]
    #pragma unroll
    for (int mt = 0; mt < 4; mt++)
        #pragma unroll
        for (int ct = 0; ct < 4; ct++)
            acc[mt][ct] = (float4v)(0.f);

    float4 regA[2][2][2];        // [buf][qq][pair]
    short8v bf[2][4][2];         // [buf][ct][split]
    const float4 z4 = make_float4(0.f,0.f,0.f,0.f);

    auto loadA = [&](int buf, int step) {
        #pragma unroll
        for (int qq = 0; qq < 2; qq++) {
            int rowg = by*64 + arow + 32*qq;
            bool rvld = rowg < MROWS;
            const float4* rp = (const float4*)Ain + (size_t)(rvld ? rowg : 0)*271;
            int i0 = step*16 + 2*ai4;
            regA[buf][qq][0] = (rvld && i0     < 271) ? rp[i0]   : z4;
            regA[buf][qq][1] = (rvld && i0 + 1 < 271) ? rp[i0+1] : z4;
        }
    };
    auto loadB = [&](int buf, int step) {
        #pragma unroll
        for (int ct = 0; ct < 4; ct++)
            #pragma unroll
            for (int s = 0; s < NSPLIT; s++)
                bf[buf][ct][s] = *(const short8v*)(pB[ct] + ((s*17 + step) << 9));
    };

    loadA(0, 0); loadB(0, 0);

    #pragma unroll 2
    for (int step = 0; step < 17; step++) {
        int cur = step & 1, nxt = cur ^ 1;
        // stage A tile into LDS with rounded 2-way bf16 split
        #pragma unroll
        for (int qq = 0; qq < 2; qq++) {
            int rl = 2*(arow + 32*qq);
            int offE = rl*40 + 4*ai4;
            float4 f0 = regA[cur][qq][0], f1 = regA[cur][qq][1];
            unsigned e0a,e1a, e0b,e1b;
            split2_pack_pair(f0.x, f0.y, e0a, e1a);
            split2_pack_pair(f1.x, f1.y, e0b, e1b);
            *(uint2*)(As + 0*APL + offE) = make_uint2(e0a, e0b);
            *(uint2*)(As + 1*APL + offE) = make_uint2(e1a, e1b);
            unsigned o0a,o1a, o0b,o1b;
            split2_pack_pair(f0.z, f0.w, o0a, o1a);
            split2_pack_pair(f1.z, f1.w, o0b, o1b);
            int offO = offE + 40;
            *(uint2*)(As + 0*APL + offO) = make_uint2(o0a, o0b);
            *(uint2*)(As + 1*APL + offO) = make_uint2(o1a, o1b);
        }
        __syncthreads();

        if (step + 1 < 17) { loadA(nxt, step+1); loadB(nxt, step+1); }

        #pragma unroll
        for (int sa = 0; sa < 2; sa++) {
            short8v af[4];
            #pragma unroll
            for (int mt = 0; mt < 4; mt++)
                af[mt] = *(const short8v*)(As + sa*APL + aoff0 + mt*16*40);
            #pragma unroll
            for (int sb = 0; sb + sa < 2; sb++)
                #pragma unroll
                for (int mt = 0; mt < 4; mt++)
                    #pragma unroll
                    for (int ct = 0; ct < 4; ct++)
                        acc[mt][ct] = __builtin_amdgcn_mfma_f32_16x16x32_bf16(
                            af[mt], bf[cur][ct][sb], acc[mt][ct], 0, 0, 0);
        }
        __syncthreads();
    }

    // ---- epilogue: twiddle combine, LDS transpose (64v1 x 64cols), coalesced writes
    float2 tg[2];
    #pragma unroll
    for (int g = 0; g < 2; g++) {
        int v1g = (bx*4 + wy*2 + g)*16 + l15;
        tg[g] = tw542[(v1g < HH) ? v1g : 0];
        if (conjtw) tg[g].y = -tg[g].y;
    }

    int lanec = tid & 31;
    int c0 = lanec*2;
    int r0g = by*64 + c0;                 // even complex col; float4 never straddles plane
    bool rok = r0g < MROWS;
    int plane = rok ? (r0g / HH) : 0;
    int colg = r0g - plane*HH;
    int n1, n2; pair_chans(plane, n1, n2);
    int b1 = n1/3, b2 = n2/3;

    #pragma unroll
    for (int half = 0; half < 2; half++) {
        __syncthreads();
        #pragma unroll
        for (int mt = 0; mt < 4; mt++) {
            #pragma unroll
            for (int g = 0; g < 2; g++) {
                #pragma unroll
                for (int pr = 0; pr < 2; pr++) {
                    float Ere = acc[mt][g*2  ][2*pr], Ore = acc[mt][g*2  ][2*pr+1];
                    float Eim = acc[mt][g*2+1][2*pr], Oim = acc[mt][g*2+1][2*pr+1];
                    float tOre = tg[g].x*Ore - tg[g].y*Oim;
                    float tOim = tg[g].x*Oim + tg[g].y*Ore;
                    int v1loc = (wy*2 + g)*16 + l15;
                    int cloc = wxm*32 + mt*8 + quad*2 + pr;
                    float2 v = (half == 0)
                        ? make_float2((Ere + tOre)*scale, (Eim + tOim)*scale)
                        : make_float2((Ere - tOre)*scale, (Eim - tOim)*scale);
                    Ts[v1loc*66 + cloc] = v;
                }
            }
        }
        __syncthreads();
        #pragma unroll
        for (int it = 0; it < 8; it++) {
            int v1loc = (tid >> 5) + it*8;
            int v1g = bx*64 + v1loc;
            if (v1g >= KH || !rok) continue;
            int v1 = v1g + (half ? KH : 0);
            float2 a0 = Ts[v1loc*66 + c0];
            float2 a1 = Ts[v1loc*66 + c0 + 1];
            size_t sp = (size_t)v1*HH + colg;
            if (mode == 0) {
                *(float4*)(Aout + (size_t)plane*NPIX + sp) =
                    make_float4(a0.x, a0.y, a1.x, a1.y);
            } else if (mode == 1) {
                float ar1 = valp[b1*2*HH + v1];
                float ar2 = valp[b2*2*HH + v1];
                float ac1a = valp[(b1*2+1)*HH + colg];
                float ac1b = valp[(b1*2+1)*HH + colg + 1];
                float ac2a = valp[(b2*2+1)*HH + colg];
                float ac2b = valp[(b2*2+1)*HH + colg + 1];
                float2* p1 = (float2*)(R0 + (size_t)n1*NPIX + sp);
                float2* p2 = (float2*)(R0 + (size_t)n2*NPIX + sp);
                float2 o1 = *p1, o2 = *p2;
                float nv1a = fmaf(ar1*ac1a, o1.x - a0.x, a0.x);
                float nv1b = fmaf(ar1*ac1b, o1.y - a1.x, a1.x);
                float nv2a = fmaf(ar2*ac2a, o2.x - a0.y, a0.y);
                float nv2b = fmaf(ar2*ac2b, o2.y - a1.y, a1.y);
                *p1 = make_float2(nv1a, nv1b);
                *p2 = make_float2(nv2a, nv2b);
                *(float4*)(Aout + (size_t)plane*NPIX + sp) =
                    make_float4(nv1a, nv2a, nv1b, nv2b);
            } else {
                *(float2*)(outbuf + (size_t)n1*NPIX + sp) = make_float2(a0.x, a1.x);
                *(float2*)(outbuf + (size_t)n2*NPIX + sp) = make_float2(a0.y, a1.y);
            }
        }
    }
}

extern "C" void kernel_launch(void* const* d_in, const int* in_sizes, int n_in,
                              void* d_out, int out_size, void* d_ws, size_t ws_size,
                              hipStream_t stream) {
    const float* y    = (const float*)d_in[0];
    const float* k    = (const float*)d_in[1];
    const float* lam  = (const float*)d_in[2];
    const float* filt = (const float*)d_in[3];
    float* out = (float*)d_out;

    char* base = (char*)d_ws;
    size_t off = 0;
    auto alloc = [&](size_t bytes) {
        void* p = base + off;
        off = (off + bytes + 511) & ~(size_t)511;
        return p;
    };
    float2* CA   = (float2*)alloc(sizeof(float2)*(size_t)NP*NPIX);
    float2* CB   = (float2*)alloc(sizeof(float2)*(size_t)NP*NPIX);
    float*  R0   = (float*) alloc(sizeof(float)*(size_t)NCH*NPIX);
    float2* Dk   = (float2*)alloc(sizeof(float2)*(size_t)BB*NPIX);
    float2* T1   = (float2*)alloc(sizeof(float2)*(size_t)BB*KSZ*HH);
    float*  Dgs  = (float*) alloc(sizeof(float)*(size_t)CC3*NPIX);
    short*  Btf  = (short*) alloc(sizeof(short)*(size_t)BTSZ);
    short*  Bti  = (short*) alloc(sizeof(short)*(size_t)BTSZ);
    float2* tw   = (float2*)alloc(sizeof(float2)*(size_t)HH);
    float*  valp = (float*) alloc(sizeof(float)*(size_t)BB*2*HH);
    (void)ws_size; (void)in_sizes; (void)n_in; (void)out_size;

    const int TPB = 256;
    auto nb = [](long n) { return (int)((n + 255)/256); };

    gen_tables<<<nb((long)BTSZ), TPB, 0, stream>>>(tw, Btf, Bti);
    alpha_kernel<<<BB, 64, 0, stream>>>(k, valp);
    dk_stage1<<<nb((long)BB*KSZ*HH), TPB, 0, stream>>>(k, tw, T1);
    dk_stage2<<<8*136*3, TPB, 0, stream>>>(T1, tw, Dk);
    dgs_kernel<<<nb((long)NPIX), TPB, 0, stream>>>(filt, lam, tw, Dgs);
    pad_pack<<<nb((long)NP*NPIX), TPB, 0, stream>>>(y, R0, CA);

    const int FG = 512;   // 8 XCDs x 64 (510 active)
    const float isc = 1.0f/(float)HH;
    float2 *S = CA, *T = CB;
    fft_mfma<<<FG, TPB, 0, stream>>>(S, T, Btf, tw, valp, R0, out, 1.0f, 0, 0);
    fft_mfma<<<FG, TPB, 0, stream>>>(T, S, Btf, tw, valp, R0, out, 1.0f, 0, 0);
    for (int it = 0; it < 3; it++) {
        specmul<<<nb((long)NP*NPIX), TPB, 0, stream>>>(S, Dk, Dgs, T, 0);
        fft_mfma<<<FG, TPB, 0, stream>>>(T, S, Bti, tw, valp, R0, out, isc, 1, 0);
        fft_mfma<<<FG, TPB, 0, stream>>>(S, T, Bti, tw, valp, R0, out, isc, 1, 1);
        fft_mfma<<<FG, TPB, 0, stream>>>(T, S, Btf, tw, valp, R0, out, 1.0f, 0, 0);
        fft_mfma<<<FG, TPB, 0, stream>>>(S, T, Btf, tw, valp, R0, out, 1.0f, 0, 0);
        float2* tmp = S; S = T; T = tmp;
    }
    specmul<<<nb((long)NP*NPIX), TPB, 0, stream>>>(S, Dk, Dgs, T, 1);
    fft_mfma<<<FG, TPB, 0, stream>>>(T, S, Bti, tw, valp, R0, out, isc, 1, 0);
    fft_mfma<<<FG, TPB, 0, stream>>>(S, T, Bti, tw, valp, R0, out, isc, 1, 2);
}